// Round 1
// baseline (1125.442 us; speedup 1.0000x reference)
//
#include <hip/hip_runtime.h>
#include <cstdint>

#define N_T 1024
#define M_V 50000
#define DIMS 256
#define CBLK 196            // ceil(50000/256)
#define NPART (CBLK * 64)   // final-kernel partial count

constexpr float ALPHA    = 0.05f;
constexpr float INV_ALPHA = 20.0f;
constexpr float A_VAL    = 1.0f / 1024.0f;
constexpr float B_VAL    = 1.0f / 50000.0f;
constexpr float THR      = 0.005f;
constexpr float EPSV     = 1e-16f;

__device__ __forceinline__ float blockReduce256(float val) {
  #pragma unroll
  for (int off = 32; off; off >>= 1) val += __shfl_down(val, off, 64);
  __shared__ float red[4];
  int lane = threadIdx.x & 63;
  int wid  = threadIdx.x >> 6;
  if (lane == 0) red[wid] = val;
  __syncthreads();
  float r = 0.0f;
  if (threadIdx.x == 0) r = red[0] + red[1] + red[2] + red[3];
  return r;
}

// ---- row sum of squares: one block (256 thr) per row, DIMS==256 ----
__global__ __launch_bounds__(256) void sumsq_kernel(const float* __restrict__ in,
                                                    float* __restrict__ o, int rows) {
  int r = blockIdx.x;
  if (r >= rows) return;
  float v = in[(size_t)r * DIMS + threadIdx.x];
  float s = blockReduce256(v * v);
  if (threadIdx.x == 0) o[r] = s;
}

// ---- GEMM + Gibbs kernel: K[i][j] = exp(-alpha*(xx_i + yy_j - 2*x_i.y_j)) ----
#define BM 64
#define BN 64
#define BK 32
__global__ __launch_bounds__(256) void gemm_k_kernel(const float* __restrict__ x,
                                                     const float* __restrict__ y,
                                                     const float* __restrict__ xx,
                                                     const float* __restrict__ yy,
                                                     float* __restrict__ Kmat) {
  __shared__ float As[BK][BM];      // As[k][i]
  __shared__ float Bs[BK][BN + 1];  // Bs[k][j]
  int tid = threadIdx.x;
  int i0 = blockIdx.y * BM;
  int j0 = blockIdx.x * BN;
  int tx = tid & 15, ty = tid >> 4;
  float acc[4][4] = {};
  for (int k0 = 0; k0 < DIMS; k0 += BK) {
    #pragma unroll
    for (int l = tid; l < 512; l += 256) {        // 64 rows x 8 float4
      int r = l >> 3, kq = l & 7;
      float4 a4 = *(const float4*)&x[(size_t)(i0 + r) * DIMS + k0 + kq * 4];
      As[kq * 4 + 0][r] = a4.x; As[kq * 4 + 1][r] = a4.y;
      As[kq * 4 + 2][r] = a4.z; As[kq * 4 + 3][r] = a4.w;
    }
    #pragma unroll
    for (int l = tid; l < 512; l += 256) {
      int r = l >> 3, kq = l & 7;
      int j = j0 + r;
      float4 b4 = make_float4(0.f, 0.f, 0.f, 0.f);
      if (j < M_V) b4 = *(const float4*)&y[(size_t)j * DIMS + k0 + kq * 4];
      Bs[kq * 4 + 0][r] = b4.x; Bs[kq * 4 + 1][r] = b4.y;
      Bs[kq * 4 + 2][r] = b4.z; Bs[kq * 4 + 3][r] = b4.w;
    }
    __syncthreads();
    #pragma unroll
    for (int k = 0; k < BK; ++k) {
      float a[4], b[4];
      #pragma unroll
      for (int r = 0; r < 4; ++r) a[r] = As[k][ty * 4 + r];
      #pragma unroll
      for (int c = 0; c < 4; ++c) b[c] = Bs[k][tx * 4 + c];
      #pragma unroll
      for (int r = 0; r < 4; ++r)
        #pragma unroll
        for (int c = 0; c < 4; ++c) acc[r][c] += a[r] * b[c];
    }
    __syncthreads();
  }
  #pragma unroll
  for (int r = 0; r < 4; ++r) {
    int i = i0 + ty * 4 + r;
    float xxi = xx[i];
    #pragma unroll
    for (int c = 0; c < 4; ++c) {
      int j = j0 + tx * 4 + c;
      if (j < M_V) {
        float m = xxi + yy[j] - 2.0f * acc[r][c];
        Kmat[(size_t)i * M_V + j] = __expf(-ALPHA * m);
      }
    }
  }
}

// ---- init ----
__global__ void init_kernel(float* u, int* done, float* errAcc) {
  int t = blockIdx.x * 256 + threadIdx.x;
  if (t < N_T) u[t] = A_VAL;
  if (t == 0) { *done = 0; *errAcc = 0.0f; }
}

__global__ void zero_scalar_kernel(float* p) { *p = 0.0f; }

// ---- column pass: s_j = (K^T u)_j ; if !CHECK, fused v update ----
template <int CHECK>
__global__ __launch_bounds__(256) void colpass_kernel(const float* __restrict__ Kmat,
                                                      const float* __restrict__ u,
                                                      float* __restrict__ v,
                                                      float* __restrict__ s_out,
                                                      const int* __restrict__ done) {
  if (*done) return;
  __shared__ float su[N_T];
  for (int i = threadIdx.x; i < N_T; i += 256) su[i] = u[i];
  __syncthreads();
  int j = blockIdx.x * 256 + threadIdx.x;
  if (j >= M_V) return;
  const float* col = Kmat + j;
  float s = 0.0f;
  #pragma unroll 8
  for (int i = 0; i < N_T; ++i) s += col[(size_t)i * M_V] * su[i];
  if (CHECK) s_out[j] = s;
  else       v[j] = B_VAL / (s + EPSV);
}

// ---- err = sum_j |v_j * s_j - b| (only on check iterations) ----
__global__ __launch_bounds__(256) void err_kernel(const float* __restrict__ v,
                                                  const float* __restrict__ s,
                                                  float* errAcc, const int* __restrict__ done) {
  if (*done) return;
  int j = blockIdx.x * 256 + threadIdx.x;
  float t = 0.0f;
  if (j < M_V) t = fabsf(v[j] * s[j] - B_VAL);
  t = blockReduce256(t);
  if (threadIdx.x == 0) atomicAdd(errAcc, t);
}

__global__ void err_check_kernel(const float* errAcc, int* done) {
  if (*errAcc <= THR) *done = 1;
}

__global__ __launch_bounds__(256) void vupdate_kernel(const float* __restrict__ s,
                                                      float* __restrict__ v,
                                                      const int* __restrict__ done) {
  if (*done) return;
  int j = blockIdx.x * 256 + threadIdx.x;
  if (j < M_V) v[j] = B_VAL / (s[j] + EPSV);
}

// ---- row pass: u_i = a / ((K v)_i + eps), one block per row ----
__global__ __launch_bounds__(256) void rowpass_kernel(const float* __restrict__ Kmat,
                                                      const float* __restrict__ v,
                                                      float* __restrict__ u,
                                                      const int* __restrict__ done) {
  if (*done) return;
  int i = blockIdx.x;
  const float* row = Kmat + (size_t)i * M_V;
  float p = 0.0f;
  for (int j = threadIdx.x; j < M_V; j += 256) p += row[j] * v[j];
  p = blockReduce256(p);
  if (threadIdx.x == 0) u[i] = A_VAL / (p + EPSV);
}

// ---- final: transp = u_i K_ij v_j -> out[1+idx]; loss partials ----
// NOTE: no __restrict__ on Kmat/out — they may alias (fallback K-in-out mode).
__global__ __launch_bounds__(256) void final_kernel(const float* Kmat,
                                                    const float* __restrict__ u,
                                                    const float* __restrict__ v,
                                                    float* out,
                                                    float* __restrict__ partials) {
  int j = blockIdx.x * 256 + threadIdx.x;
  float contrib = 0.0f;
  if (j < M_V) {
    float vj = v[j];
    #pragma unroll 4
    for (int r = 0; r < 16; ++r) {
      int i = blockIdx.y * 16 + r;
      size_t idx = (size_t)i * M_V + j;
      float k = Kmat[idx];
      float tr = u[i] * k * vj;
      float m = -__logf(k) * INV_ALPHA;
      out[1 + idx] = tr;
      contrib += tr * m;
    }
  }
  contrib = blockReduce256(contrib);
  if (threadIdx.x == 0) partials[blockIdx.y * gridDim.x + blockIdx.x] = contrib;
}

__global__ __launch_bounds__(256) void finish_kernel(const float* __restrict__ partials,
                                                     float* out, int np_) {
  float s = 0.0f;
  for (int i = threadIdx.x; i < np_; i += 256) s += partials[i];
  s = blockReduce256(s);
  if (threadIdx.x == 0) out[0] = s;
}

extern "C" void kernel_launch(void* const* d_in, const int* in_sizes, int n_in,
                              void* d_out, int out_size, void* d_ws, size_t ws_size,
                              hipStream_t stream) {
  const float* x = (const float*)d_in[0];
  const float* y = (const float*)d_in[1];
  float* out = (float*)d_out;

  uintptr_t wp = (uintptr_t)d_ws;
  auto alloc = [&](size_t bytes) -> void* {
    wp = (wp + 255) & ~(uintptr_t)255;
    void* p = (void*)wp;
    wp += bytes;
    return p;
  };
  float* u        = (float*)alloc((size_t)N_T * 4);
  float* v        = (float*)alloc((size_t)M_V * 4);
  float* s        = (float*)alloc((size_t)M_V * 4);
  float* xx       = (float*)alloc((size_t)N_T * 4);
  float* yy       = (float*)alloc((size_t)M_V * 4);
  float* partials = (float*)alloc((size_t)NPART * 4);
  int*   done     = (int*)alloc(4);
  float* errAcc   = (float*)alloc(4);
  wp = (wp + 255) & ~(uintptr_t)255;
  size_t used = wp - (uintptr_t)d_ws;

  const size_t kbytes = (size_t)N_T * M_V * 4;
  float* Kmat;
  if (ws_size >= used + kbytes) {
    Kmat = (float*)alloc(kbytes);
  } else {
    Kmat = out + 1;  // fallback: K lives in the output buffer, overwritten in-place by transp
  }

  // norms
  sumsq_kernel<<<N_T, 256, 0, stream>>>(x, xx, N_T);
  sumsq_kernel<<<M_V, 256, 0, stream>>>(y, yy, M_V);

  // K = exp(-alpha * M)
  dim3 ggrid((M_V + BN - 1) / BN, N_T / BM);
  gemm_k_kernel<<<ggrid, 256, 0, stream>>>(x, y, xx, yy, Kmat);

  init_kernel<<<(N_T + 255) / 256, 256, 0, stream>>>(u, done, errAcc);

  // Sinkhorn loop. Reference checks err only at cpt==1 and cpt==51; the err for
  // cpt=c uses K^T u_c, which is exactly iteration (c+1)'s column pass -> fuse.
  for (int t = 1; t <= 100; ++t) {
    bool check = (t == 2 || t == 52);
    if (check) {
      zero_scalar_kernel<<<1, 1, 0, stream>>>(errAcc);
      colpass_kernel<1><<<CBLK, 256, 0, stream>>>(Kmat, u, v, s, done);
      err_kernel<<<CBLK, 256, 0, stream>>>(v, s, errAcc, done);
      err_check_kernel<<<1, 1, 0, stream>>>(errAcc, done);
      vupdate_kernel<<<CBLK, 256, 0, stream>>>(s, v, done);
    } else {
      colpass_kernel<0><<<CBLK, 256, 0, stream>>>(Kmat, u, v, s, done);
    }
    rowpass_kernel<<<N_T, 256, 0, stream>>>(Kmat, v, u, done);
  }

  // transp + loss
  dim3 fgrid(CBLK, 64);
  final_kernel<<<fgrid, 256, 0, stream>>>(Kmat, u, v, out, partials);
  finish_kernel<<<1, 256, 0, stream>>>(partials, out, NPART);
}

// Round 2
// 828.551 us; speedup vs baseline: 1.3583x; 1.3583x over previous
//
#include <hip/hip_runtime.h>
#include <hip/hip_cooperative_groups.h>
#include <cstdint>

namespace cg = cooperative_groups;

#define N_T 1024
#define M_V 50000
#define DIMS 256
#define KPACK 768
#define NPAD 50048
#define CBLK 196            // ceil(50000/256) for final kernel
#define NPART (CBLK * 64)
#define NCHUNK 782          // ceil(50000/64) column chunks in coop colpass
#define COOP_BLOCKS 1024

constexpr float ALPHA     = 0.05f;
constexpr float INV_ALPHA = 20.0f;
constexpr float A_VAL     = 1.0f / 1024.0f;
constexpr float B_VAL     = 1.0f / 50000.0f;
constexpr float THR       = 0.005f;
constexpr float EPSV      = 1e-16f;

typedef short bf16x8 __attribute__((ext_vector_type(8)));
typedef float f32x4  __attribute__((ext_vector_type(4)));

__device__ __forceinline__ float blockReduce256(float val) {
  #pragma unroll
  for (int off = 32; off; off >>= 1) val += __shfl_down(val, off, 64);
  __shared__ float redw[4];
  int lane = threadIdx.x & 63;
  int wid  = threadIdx.x >> 6;
  if (lane == 0) redw[wid] = val;
  __syncthreads();
  float r = 0.0f;
  if (threadIdx.x == 0) r = redw[0] + redw[1] + redw[2] + redw[3];
  __syncthreads();
  return r;
}

__device__ __forceinline__ unsigned short f2bf(float f) {
  union { float f; unsigned u; } c{f};
  unsigned r = c.u + 0x7FFF + ((c.u >> 16) & 1);   // RNE
  return (unsigned short)(r >> 16);
}
__device__ __forceinline__ float bf2f(unsigned short b) {
  union { unsigned u; float f; } c{(unsigned)b << 16};
  return c.f;
}

__device__ __forceinline__ void gload16(const void* g, void* l) {
  __builtin_amdgcn_global_load_lds((const __attribute__((address_space(1))) unsigned int*)g,
                                   (__attribute__((address_space(3))) unsigned int*)l, 16, 0, 0);
}

// ---- row sum of squares (exact f32): one block per row, DIMS==256 ----
__global__ __launch_bounds__(256) void sumsq_kernel(const float* __restrict__ in,
                                                    float* __restrict__ o, int rows) {
  int r = blockIdx.x;
  if (r >= rows) return;
  float v = in[(size_t)r * DIMS + threadIdx.x];
  float s = blockReduce256(v * v);
  if (threadIdx.x == 0) o[r] = s;
}

// ---- pack x -> A' = [xh | xl | xh]  (2 rows per block, 128 thr/row, 2 elems/thr) ----
__global__ __launch_bounds__(256) void pack_x_kernel(const float* __restrict__ x,
                                                     unsigned short* __restrict__ Ap) {
  int r = blockIdx.x * 2 + (threadIdx.x >> 7);
  int k = (threadIdx.x & 127) * 2;
  float2 vx = *(const float2*)&x[(size_t)r * DIMS + k];
  ushort2 h2, l2;
  h2.x = f2bf(vx.x); h2.y = f2bf(vx.y);
  l2.x = f2bf(vx.x - bf2f(h2.x)); l2.y = f2bf(vx.y - bf2f(h2.y));
  *(ushort2*)&Ap[(size_t)r * KPACK + k]           = h2;
  *(ushort2*)&Ap[(size_t)r * KPACK + DIMS + k]    = l2;
  *(ushort2*)&Ap[(size_t)r * KPACK + 2*DIMS + k]  = h2;
}

// ---- pack y -> B' = [yh | yh | yl], rows >= 50000 zero-padded ----
__global__ __launch_bounds__(256) void pack_y_kernel(const float* __restrict__ y,
                                                     unsigned short* __restrict__ Bp) {
  int r = blockIdx.x * 2 + (threadIdx.x >> 7);
  int k = (threadIdx.x & 127) * 2;
  ushort2 h2 = {0, 0}, l2 = {0, 0};
  if (r < M_V) {
    float2 vy = *(const float2*)&y[(size_t)r * DIMS + k];
    h2.x = f2bf(vy.x); h2.y = f2bf(vy.y);
    l2.x = f2bf(vy.x - bf2f(h2.x)); l2.y = f2bf(vy.y - bf2f(h2.y));
  }
  *(ushort2*)&Bp[(size_t)r * KPACK + k]          = h2;
  *(ushort2*)&Bp[(size_t)r * KPACK + DIMS + k]   = h2;
  *(ushort2*)&Bp[(size_t)r * KPACK + 2*DIMS + k] = l2;
}

// ---- MFMA GEMM + Gibbs epilogue: K[i][j] = exp(-a*(xx_i + yy_j - 2*Ap.Bp)) ----
// 128x128 tile, BK=32, 4 waves each 64x64 (4x4 frags of 16x16x32 bf16).
__global__ __launch_bounds__(256) void mfma_gemm_kernel(const unsigned short* __restrict__ Ap,
                                                        const unsigned short* __restrict__ Bp,
                                                        const float* __restrict__ xx,
                                                        const float* __restrict__ yy,
                                                        float* Kmat) {
  __shared__ unsigned short As[128][32];
  __shared__ unsigned short Bs[128][32];
  const int tid  = threadIdx.x;
  const int lane = tid & 63;
  const int wid  = tid >> 6;
  const int wr = wid >> 1, wc = wid & 1;
  const int i0 = blockIdx.y * 128;
  const int j0 = blockIdx.x * 128;

  f32x4 acc[4][4];
  #pragma unroll
  for (int m = 0; m < 4; ++m)
    #pragma unroll
    for (int n = 0; n < 4; ++n) acc[m][n] = (f32x4){0.f, 0.f, 0.f, 0.f};

  const int srow   = lane >> 2;   // 0..15 within 16-row issue
  const int schunk = lane & 3;    // 8-bf16 chunk within 32-wide row

  for (int k0 = 0; k0 < KPACK; k0 += 32) {
    // stage: each wave 2 issues of 1KB per matrix; LDS dest linear, global src pre-swizzled
    #pragma unroll
    for (int q = 0; q < 2; ++q) {
      int rbase = (wid * 2 + q) * 16;
      int row = rbase + srow;
      int cg_ = schunk ^ ((row ^ (row >> 2)) & 3);
      gload16(Ap + (size_t)(i0 + row) * KPACK + k0 + cg_ * 8, &As[rbase][0]);
      gload16(Bp + (size_t)(j0 + row) * KPACK + k0 + cg_ * 8, &Bs[rbase][0]);
    }
    __syncthreads();
    bf16x8 af[4], bfr[4];
    #pragma unroll
    for (int m = 0; m < 4; ++m) {
      int row = wr * 64 + m * 16 + (lane & 15);
      int ch  = (lane >> 4) ^ ((row ^ (row >> 2)) & 3);
      af[m] = *(const bf16x8*)&As[row][ch * 8];
    }
    #pragma unroll
    for (int n = 0; n < 4; ++n) {
      int col = wc * 64 + n * 16 + (lane & 15);
      int ch  = (lane >> 4) ^ ((col ^ (col >> 2)) & 3);
      bfr[n] = *(const bf16x8*)&Bs[col][ch * 8];
    }
    #pragma unroll
    for (int m = 0; m < 4; ++m)
      #pragma unroll
      for (int n = 0; n < 4; ++n)
        acc[m][n] = __builtin_amdgcn_mfma_f32_16x16x32_bf16(af[m], bfr[n], acc[m][n], 0, 0, 0);
    __syncthreads();
  }

  // epilogue: D col=lane&15, row=(lane>>4)*4+reg  [m89-verified]
  #pragma unroll
  for (int m = 0; m < 4; ++m) {
    int rowb = i0 + wr * 64 + m * 16 + (lane >> 4) * 4;
    #pragma unroll
    for (int n = 0; n < 4; ++n) {
      int col = j0 + wc * 64 + n * 16 + (lane & 15);
      if (col < M_V) {
        float yyc = yy[col];
        #pragma unroll
        for (int r = 0; r < 4; ++r) {
          float mval = xx[rowb + r] + yyc - 2.0f * acc[m][n][r];
          Kmat[(size_t)(rowb + r) * M_V + col] = __expf(-ALPHA * mval);
        }
      }
    }
  }
}

// ---- fallback f32 GEMM (round-1, used only if ws too small for bf16 packs) ----
#define BM 64
#define BN 64
#define BK 32
__global__ __launch_bounds__(256) void gemm_k_kernel(const float* __restrict__ x,
                                                     const float* __restrict__ y,
                                                     const float* __restrict__ xx,
                                                     const float* __restrict__ yy,
                                                     float* Kmat) {
  __shared__ float As[BK][BM];
  __shared__ float Bs[BK][BN + 1];
  int tid = threadIdx.x;
  int i0 = blockIdx.y * BM;
  int j0 = blockIdx.x * BN;
  int tx = tid & 15, ty = tid >> 4;
  float acc[4][4] = {};
  for (int k0 = 0; k0 < DIMS; k0 += BK) {
    #pragma unroll
    for (int l = tid; l < 512; l += 256) {
      int r = l >> 3, kq = l & 7;
      float4 a4 = *(const float4*)&x[(size_t)(i0 + r) * DIMS + k0 + kq * 4];
      As[kq * 4 + 0][r] = a4.x; As[kq * 4 + 1][r] = a4.y;
      As[kq * 4 + 2][r] = a4.z; As[kq * 4 + 3][r] = a4.w;
    }
    #pragma unroll
    for (int l = tid; l < 512; l += 256) {
      int r = l >> 3, kq = l & 7;
      int j = j0 + r;
      float4 b4 = make_float4(0.f, 0.f, 0.f, 0.f);
      if (j < M_V) b4 = *(const float4*)&y[(size_t)j * DIMS + k0 + kq * 4];
      Bs[kq * 4 + 0][r] = b4.x; Bs[kq * 4 + 1][r] = b4.y;
      Bs[kq * 4 + 2][r] = b4.z; Bs[kq * 4 + 3][r] = b4.w;
    }
    __syncthreads();
    #pragma unroll
    for (int k = 0; k < BK; ++k) {
      float a[4], b[4];
      #pragma unroll
      for (int r = 0; r < 4; ++r) a[r] = As[k][ty * 4 + r];
      #pragma unroll
      for (int c = 0; c < 4; ++c) b[c] = Bs[k][tx * 4 + c];
      #pragma unroll
      for (int r = 0; r < 4; ++r)
        #pragma unroll
        for (int c = 0; c < 4; ++c) acc[r][c] += a[r] * b[c];
    }
    __syncthreads();
  }
  #pragma unroll
  for (int r = 0; r < 4; ++r) {
    int i = i0 + ty * 4 + r;
    float xxi = xx[i];
    #pragma unroll
    for (int c = 0; c < 4; ++c) {
      int j = j0 + tx * 4 + c;
      if (j < M_V) {
        float m = xxi + yy[j] - 2.0f * acc[r][c];
        Kmat[(size_t)i * M_V + j] = __expf(-ALPHA * m);
      }
    }
  }
}

// ---- persistent cooperative Sinkhorn loop ----
template <bool AL>
__global__ __launch_bounds__(256, 4) void sinkhorn_coop(const float* Km,
                                                        float* __restrict__ u,
                                                        float* __restrict__ v,
                                                        float* __restrict__ s,
                                                        float* __restrict__ errAcc) {
  cg::grid_group grid = cg::this_grid();
  __shared__ float su[N_T];
  __shared__ float red[8][64];
  const int tid = threadIdx.x;
  const int bid = blockIdx.x;
  {
    int g0 = bid * 256 + tid;
    if (g0 < N_T) u[g0] = A_VAL;
    if (g0 < 2) errAcc[g0] = 0.0f;
  }
  grid.sync();
  for (int t = 1; t <= 100; ++t) {
    const bool check = (t == 2) || (t == 52);
    for (int i = tid; i < N_T; i += 256) su[i] = u[i];
    __syncthreads();
    // --- colpass: s_j = (K^T u)_j over 64-col chunks, 8 i-groups x 32 f2-lanes
    const int g = tid >> 5, jl = tid & 31;
    float eacc = 0.0f;
    for (int c = bid; c < NCHUNK; c += COOP_BLOCKS) {
      const int j0 = c * 64;
      const int jj = j0 + jl * 2;
      float p0 = 0.f, p1 = 0.f;
      if (jj < M_V) {
        const float* base = Km + (size_t)(g * 128) * M_V + jj;
        #pragma unroll 4
        for (int i = 0; i < 128; ++i) {
          float k0, k1;
          if (AL) {
            float2 kk = *(const float2*)(base + (size_t)i * M_V);
            k0 = kk.x; k1 = kk.y;
          } else {
            k0 = base[(size_t)i * M_V];
            k1 = base[(size_t)i * M_V + 1];
          }
          float uu = su[g * 128 + i];
          p0 += k0 * uu; p1 += k1 * uu;
        }
      }
      red[g][jl * 2]     = p0;
      red[g][jl * 2 + 1] = p1;
      __syncthreads();
      if (tid < 64) {
        int j = j0 + tid;
        if (j < M_V) {
          float st = 0.f;
          #pragma unroll
          for (int q = 0; q < 8; ++q) st += red[q][tid];
          if (check) {
            s[j] = st;
            eacc += fabsf(v[j] * st - B_VAL);   // err uses pre-update v
          } else {
            v[j] = B_VAL / (st + EPSV);
          }
        }
      }
      __syncthreads();
    }
    if (check) {
      float e = blockReduce256(eacc);
      if (tid == 0) atomicAdd(&errAcc[t == 2 ? 0 : 1], e);
    }
    grid.sync();
    if (check) {
      float e = errAcc[t == 2 ? 0 : 1];
      if (e <= THR) break;                      // uniform across grid
      if (tid < 64) {
        for (int c = bid; c < NCHUNK; c += COOP_BLOCKS) {
          int j = c * 64 + tid;
          if (j < M_V) v[j] = B_VAL / (s[j] + EPSV);
        }
      }
      grid.sync();
    }
    // --- rowpass: u_i = a / (K v)_i, one block per row
    {
      int i = bid;
      float p = 0.f;
      if (i < N_T) {
        const float* row = Km + (size_t)i * M_V;
        if (AL) {
          const float4* r4 = (const float4*)row;
          const float4* v4 = (const float4*)v;
          for (int j = tid; j < M_V / 4; j += 256) {
            float4 kk = r4[j]; float4 vv = v4[j];
            p += kk.x * vv.x + kk.y * vv.y + kk.z * vv.z + kk.w * vv.w;
          }
        } else {
          for (int j = tid; j < M_V; j += 256) p += row[j] * v[j];
        }
      }
      p = blockReduce256(p);
      if (tid == 0 && i < N_T) u[i] = A_VAL / (p + EPSV);
    }
    grid.sync();
  }
}

// ---- final: transp = u_i K_ij v_j -> out[1+idx]; loss partials ----
__global__ __launch_bounds__(256) void final_kernel(const float* Kmat,
                                                    const float* __restrict__ u,
                                                    const float* __restrict__ v,
                                                    float* out,
                                                    float* __restrict__ partials) {
  int j = blockIdx.x * 256 + threadIdx.x;
  float contrib = 0.0f;
  if (j < M_V) {
    float vj = v[j];
    #pragma unroll 4
    for (int r = 0; r < 16; ++r) {
      int i = blockIdx.y * 16 + r;
      size_t idx = (size_t)i * M_V + j;
      float k = Kmat[idx];
      float tr = u[i] * k * vj;
      float m = -__logf(k) * INV_ALPHA;
      out[1 + idx] = tr;
      contrib += tr * m;
    }
  }
  contrib = blockReduce256(contrib);
  if (threadIdx.x == 0) partials[blockIdx.y * gridDim.x + blockIdx.x] = contrib;
}

__global__ __launch_bounds__(256) void finish_kernel(const float* __restrict__ partials,
                                                     float* out, int np_) {
  float s = 0.0f;
  for (int i = threadIdx.x; i < np_; i += 256) s += partials[i];
  s = blockReduce256(s);
  if (threadIdx.x == 0) out[0] = s;
}

extern "C" void kernel_launch(void* const* d_in, const int* in_sizes, int n_in,
                              void* d_out, int out_size, void* d_ws, size_t ws_size,
                              hipStream_t stream) {
  const float* x = (const float*)d_in[0];
  const float* y = (const float*)d_in[1];
  float* out = (float*)d_out;

  uintptr_t wp = (uintptr_t)d_ws;
  uintptr_t wend = (uintptr_t)d_ws + ws_size;
  auto alloc = [&](size_t bytes) -> void* {
    wp = (wp + 255) & ~(uintptr_t)255;
    void* p = (void*)wp;
    wp += bytes;
    return p;
  };
  float* u        = (float*)alloc((size_t)N_T * 4);
  float* v        = (float*)alloc((size_t)M_V * 4);
  float* s        = (float*)alloc((size_t)M_V * 4);
  float* xx       = (float*)alloc((size_t)N_T * 4);
  float* yy       = (float*)alloc((size_t)M_V * 4);
  float* partials = (float*)alloc((size_t)NPART * 4);
  float* errAcc   = (float*)alloc(64);

  const size_t apbytes = (size_t)N_T * KPACK * 2;
  const size_t bpbytes = (size_t)NPAD * KPACK * 2;
  const size_t kbytes  = (size_t)N_T * M_V * 4;

  bool mfma_path = ((wp + 511) + apbytes + bpbytes) <= wend;
  unsigned short* Ap = nullptr;
  unsigned short* Bp = nullptr;
  if (mfma_path) {
    Ap = (unsigned short*)alloc(apbytes);
    Bp = (unsigned short*)alloc(bpbytes);
  }
  bool k_in_ws = ((wp + 511) + kbytes) <= wend;
  float* Kmat = k_in_ws ? (float*)alloc(kbytes) : out + 1;

  // exact f32 row norms
  sumsq_kernel<<<N_T, 256, 0, stream>>>(x, xx, N_T);
  sumsq_kernel<<<M_V, 256, 0, stream>>>(y, yy, M_V);

  if (mfma_path) {
    pack_x_kernel<<<N_T / 2, 256, 0, stream>>>(x, Ap);
    pack_y_kernel<<<NPAD / 2, 256, 0, stream>>>(y, Bp);
    dim3 ggrid((M_V + 127) / 128, N_T / 128);
    mfma_gemm_kernel<<<ggrid, 256, 0, stream>>>(Ap, Bp, xx, yy, Kmat);
  } else {
    dim3 ggrid((M_V + BN - 1) / BN, N_T / BM);
    gemm_k_kernel<<<ggrid, 256, 0, stream>>>(x, y, xx, yy, Kmat);
  }

  // persistent Sinkhorn loop (single cooperative dispatch)
  void* coopArgs[] = {(void*)&Kmat, (void*)&u, (void*)&v, (void*)&s, (void*)&errAcc};
  if (k_in_ws) {
    hipLaunchCooperativeKernel(reinterpret_cast<void*>(sinkhorn_coop<true>),
                               dim3(COOP_BLOCKS), dim3(256), coopArgs, 0, stream);
  } else {
    hipLaunchCooperativeKernel(reinterpret_cast<void*>(sinkhorn_coop<false>),
                               dim3(COOP_BLOCKS), dim3(256), coopArgs, 0, stream);
  }

  // transp + loss
  dim3 fgrid(CBLK, 64);
  final_kernel<<<fgrid, 256, 0, stream>>>(Kmat, u, v, out, partials);
  finish_kernel<<<1, 256, 0, stream>>>(partials, out, NPART);
}

// Round 3
// 418.222 us; speedup vs baseline: 2.6910x; 1.9811x over previous
//
#include <hip/hip_runtime.h>
#include <hip/hip_cooperative_groups.h>
#include <cstdint>

namespace cg = cooperative_groups;

#define N_T 1024
#define M_V 50000
#define DIMS 256
#define KPACK 768
#define NPAD 50048
#define CBLK 196            // ceil(50000/256)
#define NPART (CBLK * 64)
#define NCHUNK 782          // coop colpass chunks
#define COOP_BLOCKS 1024
#define J4TOT 12500         // 50000/4 float4 columns
#define FBLK 49             // ceil(12500/256)
#define LPART (FBLK * 64)

constexpr float ALPHA     = 0.05f;
constexpr float INV_ALPHA = 20.0f;
constexpr float A_VAL     = 1.0f / 1024.0f;
constexpr float B_VAL     = 1.0f / 50000.0f;
constexpr float THR       = 0.005f;
constexpr float EPSV      = 1e-16f;

typedef short bf16x8 __attribute__((ext_vector_type(8)));
typedef float f32x4  __attribute__((ext_vector_type(4)));

__device__ __forceinline__ float blockReduce256(float val) {
  #pragma unroll
  for (int off = 32; off; off >>= 1) val += __shfl_down(val, off, 64);
  __shared__ float redw[4];
  int lane = threadIdx.x & 63;
  int wid  = threadIdx.x >> 6;
  if (lane == 0) redw[wid] = val;
  __syncthreads();
  float r = 0.0f;
  if (threadIdx.x == 0) r = redw[0] + redw[1] + redw[2] + redw[3];
  __syncthreads();
  return r;
}

__device__ __forceinline__ unsigned short f2bf(float f) {
  union { float f; unsigned u; } c{f};
  unsigned r = c.u + 0x7FFF + ((c.u >> 16) & 1);   // RNE
  return (unsigned short)(r >> 16);
}
__device__ __forceinline__ float bf2f(unsigned short b) {
  union { unsigned u; float f; } c{(unsigned)b << 16};
  return c.f;
}

__device__ __forceinline__ void gload16(const void* g, void* l) {
  __builtin_amdgcn_global_load_lds((const __attribute__((address_space(1))) unsigned int*)g,
                                   (__attribute__((address_space(3))) unsigned int*)l, 16, 0, 0);
}

// ---- row sum of squares ----
__global__ __launch_bounds__(256) void sumsq_kernel(const float* __restrict__ in,
                                                    float* __restrict__ o, int rows) {
  int r = blockIdx.x;
  if (r >= rows) return;
  float v = in[(size_t)r * DIMS + threadIdx.x];
  float s = blockReduce256(v * v);
  if (threadIdx.x == 0) o[r] = s;
}

// ---- pack x -> A' = [xh | xl | xh] ----
__global__ __launch_bounds__(256) void pack_x_kernel(const float* __restrict__ x,
                                                     unsigned short* __restrict__ Ap) {
  int r = blockIdx.x * 2 + (threadIdx.x >> 7);
  int k = (threadIdx.x & 127) * 2;
  float2 vx = *(const float2*)&x[(size_t)r * DIMS + k];
  ushort2 h2, l2;
  h2.x = f2bf(vx.x); h2.y = f2bf(vx.y);
  l2.x = f2bf(vx.x - bf2f(h2.x)); l2.y = f2bf(vx.y - bf2f(h2.y));
  *(ushort2*)&Ap[(size_t)r * KPACK + k]           = h2;
  *(ushort2*)&Ap[(size_t)r * KPACK + DIMS + k]    = l2;
  *(ushort2*)&Ap[(size_t)r * KPACK + 2*DIMS + k]  = h2;
}

// ---- pack y -> B' = [yh | yh | yl] ----
__global__ __launch_bounds__(256) void pack_y_kernel(const float* __restrict__ y,
                                                     unsigned short* __restrict__ Bp) {
  int r = blockIdx.x * 2 + (threadIdx.x >> 7);
  int k = (threadIdx.x & 127) * 2;
  ushort2 h2 = {0, 0}, l2 = {0, 0};
  if (r < M_V) {
    float2 vy = *(const float2*)&y[(size_t)r * DIMS + k];
    h2.x = f2bf(vy.x); h2.y = f2bf(vy.y);
    l2.x = f2bf(vy.x - bf2f(h2.x)); l2.y = f2bf(vy.y - bf2f(h2.y));
  }
  *(ushort2*)&Bp[(size_t)r * KPACK + k]          = h2;
  *(ushort2*)&Bp[(size_t)r * KPACK + DIMS + k]   = h2;
  *(ushort2*)&Bp[(size_t)r * KPACK + 2*DIMS + k] = l2;
}

// ---- MFMA GEMM + Gibbs epilogue + fused column-sum partials ----
__global__ __launch_bounds__(256) void mfma_gemm_kernel(const unsigned short* __restrict__ Ap,
                                                        const unsigned short* __restrict__ Bp,
                                                        const float* __restrict__ xx,
                                                        const float* __restrict__ yy,
                                                        float* __restrict__ Kmat,
                                                        float* __restrict__ colsumPart) {
  __shared__ unsigned short As[128][32];
  __shared__ unsigned short Bs[128][32];
  const int tid  = threadIdx.x;
  const int lane = tid & 63;
  const int wid  = tid >> 6;
  const int wr = wid >> 1, wc = wid & 1;
  const int i0 = blockIdx.y * 128;
  const int j0 = blockIdx.x * 128;

  f32x4 acc[4][4];
  #pragma unroll
  for (int m = 0; m < 4; ++m)
    #pragma unroll
    for (int n = 0; n < 4; ++n) acc[m][n] = (f32x4){0.f, 0.f, 0.f, 0.f};

  const int srow   = lane >> 2;
  const int schunk = lane & 3;

  for (int k0 = 0; k0 < KPACK; k0 += 32) {
    #pragma unroll
    for (int q = 0; q < 2; ++q) {
      int rbase = (wid * 2 + q) * 16;
      int row = rbase + srow;
      int cg_ = schunk ^ ((row ^ (row >> 2)) & 3);
      gload16(Ap + (size_t)(i0 + row) * KPACK + k0 + cg_ * 8, &As[rbase][0]);
      gload16(Bp + (size_t)(j0 + row) * KPACK + k0 + cg_ * 8, &Bs[rbase][0]);
    }
    __syncthreads();
    bf16x8 af[4], bfr[4];
    #pragma unroll
    for (int m = 0; m < 4; ++m) {
      int row = wr * 64 + m * 16 + (lane & 15);
      int ch  = (lane >> 4) ^ ((row ^ (row >> 2)) & 3);
      af[m] = *(const bf16x8*)&As[row][ch * 8];
    }
    #pragma unroll
    for (int n = 0; n < 4; ++n) {
      int col = wc * 64 + n * 16 + (lane & 15);
      int ch  = (lane >> 4) ^ ((col ^ (col >> 2)) & 3);
      bfr[n] = *(const bf16x8*)&Bs[col][ch * 8];
    }
    #pragma unroll
    for (int m = 0; m < 4; ++m)
      #pragma unroll
      for (int n = 0; n < 4; ++n)
        acc[m][n] = __builtin_amdgcn_mfma_f32_16x16x32_bf16(af[m], bfr[n], acc[m][n], 0, 0, 0);
    __syncthreads();
  }

  // epilogue: D col=lane&15, row=(lane>>4)*4+reg; fused per-column K sums
  float csum[4] = {0.f, 0.f, 0.f, 0.f};
  #pragma unroll
  for (int m = 0; m < 4; ++m) {
    int rowb = i0 + wr * 64 + m * 16 + (lane >> 4) * 4;
    #pragma unroll
    for (int n = 0; n < 4; ++n) {
      int col = j0 + wc * 64 + n * 16 + (lane & 15);
      float yyc = (col < M_V) ? yy[col] : 0.0f;
      #pragma unroll
      for (int r = 0; r < 4; ++r) {
        float mval = xx[rowb + r] + yyc - 2.0f * acc[m][n][r];
        float kv = __expf(-ALPHA * mval);
        if (col < M_V) Kmat[(size_t)(rowb + r) * M_V + col] = kv;
        csum[n] += kv;
      }
    }
  }
  // reduce csum across the 4 lane-groups (same lane&15 = same column)
  #pragma unroll
  for (int n = 0; n < 4; ++n) {
    float c = csum[n];
    c += __shfl_xor(c, 16, 64);
    c += __shfl_xor(c, 32, 64);
    if (lane < 16) {
      int col = j0 + wc * 64 + n * 16 + lane;
      colsumPart[(size_t)(blockIdx.y * 2 + wr) * NPAD + col] = c;
    }
  }
}

// ---- fallback f32 GEMM ----
#define BM 64
#define BN 64
#define BK 32
__global__ __launch_bounds__(256) void gemm_k_kernel(const float* __restrict__ x,
                                                     const float* __restrict__ y,
                                                     const float* __restrict__ xx,
                                                     const float* __restrict__ yy,
                                                     float* Kmat) {
  __shared__ float As[BK][BM];
  __shared__ float Bs[BK][BN + 1];
  int tid = threadIdx.x;
  int i0 = blockIdx.y * BM;
  int j0 = blockIdx.x * BN;
  int tx = tid & 15, ty = tid >> 4;
  float acc[4][4] = {};
  for (int k0 = 0; k0 < DIMS; k0 += BK) {
    #pragma unroll
    for (int l = tid; l < 512; l += 256) {
      int r = l >> 3, kq = l & 7;
      float4 a4 = *(const float4*)&x[(size_t)(i0 + r) * DIMS + k0 + kq * 4];
      As[kq * 4 + 0][r] = a4.x; As[kq * 4 + 1][r] = a4.y;
      As[kq * 4 + 2][r] = a4.z; As[kq * 4 + 3][r] = a4.w;
    }
    #pragma unroll
    for (int l = tid; l < 512; l += 256) {
      int r = l >> 3, kq = l & 7;
      int j = j0 + r;
      float4 b4 = make_float4(0.f, 0.f, 0.f, 0.f);
      if (j < M_V) b4 = *(const float4*)&y[(size_t)j * DIMS + k0 + kq * 4];
      Bs[kq * 4 + 0][r] = b4.x; Bs[kq * 4 + 1][r] = b4.y;
      Bs[kq * 4 + 2][r] = b4.z; Bs[kq * 4 + 3][r] = b4.w;
    }
    __syncthreads();
    #pragma unroll
    for (int k = 0; k < BK; ++k) {
      float a[4], b[4];
      #pragma unroll
      for (int r = 0; r < 4; ++r) a[r] = As[k][ty * 4 + r];
      #pragma unroll
      for (int c = 0; c < 4; ++c) b[c] = Bs[k][tx * 4 + c];
      #pragma unroll
      for (int r = 0; r < 4; ++r)
        #pragma unroll
        for (int c = 0; c < 4; ++c) acc[r][c] += a[r] * b[c];
    }
    __syncthreads();
  }
  #pragma unroll
  for (int r = 0; r < 4; ++r) {
    int i = i0 + ty * 4 + r;
    float xxi = xx[i];
    #pragma unroll
    for (int c = 0; c < 4; ++c) {
      int j = j0 + tx * 4 + c;
      if (j < M_V) {
        float m = xxi + yy[j] - 2.0f * acc[r][c];
        Kmat[(size_t)i * M_V + j] = __expf(-ALPHA * m);
      }
    }
  }
}

// ---- v1: v_j = b / (colsum_j * a + eps); also zero errAcc ----
__global__ __launch_bounds__(256) void v1_kernel(const float* __restrict__ cp,
                                                 float* __restrict__ v,
                                                 float* __restrict__ errAcc) {
  int j = blockIdx.x * 256 + threadIdx.x;
  if (j == 0) errAcc[0] = 0.0f;
  if (j < M_V) {
    float s = 0.0f;
    #pragma unroll
    for (int q = 0; q < 16; ++q) s += cp[(size_t)q * NPAD + j];
    v[j] = B_VAL / (s * A_VAL + EPSV);
  }
}

// ---- rowpass: partial (K v) per (row, quarter-chunk); high-MLP float4 stream ----
__global__ __launch_bounds__(256) void rowpass_kernel(const float* __restrict__ Km,
                                                      const float* __restrict__ v,
                                                      float* __restrict__ rowPart) {
  const int i = blockIdx.y;
  const int c = blockIdx.x;
  const float4* K4 = (const float4*)(Km + (size_t)i * M_V);
  const float4* v4 = (const float4*)v;
  const int base = c * 3125;
  float p = 0.0f;
  int q = base + threadIdx.x;
  #pragma unroll
  for (int it = 0; it < 12; ++it) {
    float4 k = K4[q], w = v4[q];
    p += k.x * w.x + k.y * w.y + k.z * w.z + k.w * w.w;
    q += 256;
  }
  if (q < base + 3125) {
    float4 k = K4[q], w = v4[q];
    p += k.x * w.x + k.y * w.y + k.z * w.z + k.w * w.w;
  }
  p = blockReduce256(p);
  if (threadIdx.x == 0) rowPart[c * N_T + i] = p;
}

__global__ void u_kernel(const float* __restrict__ rowPart, float* __restrict__ u) {
  int i = blockIdx.x * 256 + threadIdx.x;
  float s = rowPart[i] + rowPart[N_T + i] + rowPart[2 * N_T + i] + rowPart[3 * N_T + i];
  u[i] = A_VAL / (s + EPSV);
}

// ---- speculative final: transp write + loss partials + s=K^T u partials ----
__global__ __launch_bounds__(256) void specfinal_kernel(const float* __restrict__ Km,
                                                        const float* __restrict__ u_,
                                                        const float* __restrict__ v_,
                                                        float* __restrict__ out,
                                                        float* __restrict__ sPart,
                                                        float* __restrict__ lossPart) {
  const int j4 = blockIdx.x * 256 + threadIdx.x;
  const int by = blockIdx.y;
  float contrib = 0.0f;
  if (j4 < J4TOT) {
    float4 vv = ((const float4*)v_)[j4];
    float4 sp = {0.f, 0.f, 0.f, 0.f};
    const size_t jb = (size_t)j4 * 4;
    #pragma unroll
    for (int r = 0; r < 16; ++r) {
      int i = by * 16 + r;
      float4 k = ((const float4*)(Km + (size_t)i * M_V))[j4];
      float ui = u_[i];
      float tx_ = ui * k.x * vv.x, ty_ = ui * k.y * vv.y;
      float tz_ = ui * k.z * vv.z, tw_ = ui * k.w * vv.w;
      size_t o = 1 + (size_t)i * M_V + jb;
      out[o] = tx_; out[o + 1] = ty_; out[o + 2] = tz_; out[o + 3] = tw_;
      contrib += tx_ * (-__logf(k.x)) + ty_ * (-__logf(k.y))
               + tz_ * (-__logf(k.z)) + tw_ * (-__logf(k.w));
      sp.x += k.x * ui; sp.y += k.y * ui; sp.z += k.z * ui; sp.w += k.w * ui;
    }
    ((float4*)(sPart + (size_t)by * M_V))[j4] = sp;
  }
  contrib = blockReduce256(contrib) * INV_ALPHA;
  if (threadIdx.x == 0) lossPart[by * FBLK + blockIdx.x] = contrib;
}

// ---- err = sum_j |v_j * s_j - b| from sPart ----
__global__ __launch_bounds__(256) void errfinish_kernel(const float* __restrict__ sPart,
                                                        const float* __restrict__ v_,
                                                        float* errAcc) {
  int j = blockIdx.x * 256 + threadIdx.x;
  float e = 0.0f;
  if (j < M_V) {
    float s = 0.0f;
    #pragma unroll
    for (int q = 0; q < 64; ++q) s += sPart[(size_t)q * M_V + j];
    e = fabsf(v_[j] * s - B_VAL);
  }
  e = blockReduce256(e);
  if (threadIdx.x == 0) atomicAdd(errAcc, e);
}

__global__ void setflag_kernel(const float* errAcc, int* notconv) {
  *notconv = (errAcc[0] > THR) ? 1 : 0;
}

__global__ void set1_kernel(int* p) { *p = 1; }

__global__ __launch_bounds__(256) void finishloss_kernel(const float* __restrict__ lossPart,
                                                         float* out, int np_) {
  float s = 0.0f;
  for (int i = threadIdx.x; i < np_; i += 256) s += lossPart[i];
  s = blockReduce256(s);
  if (threadIdx.x == 0) out[0] = s;
}

// ---- safety-net cooperative Sinkhorn loop (gated; full reference semantics) ----
template <bool AL>
__global__ __launch_bounds__(256, 4) void sinkhorn_coop(const float* Km,
                                                        float* __restrict__ u,
                                                        float* __restrict__ v,
                                                        float* __restrict__ s,
                                                        float* __restrict__ errAcc,
                                                        const int* __restrict__ notconv) {
  if (*notconv == 0) return;   // uniform across grid: no one syncs
  cg::grid_group grid = cg::this_grid();
  __shared__ float su[N_T];
  __shared__ float red[8][64];
  const int tid = threadIdx.x;
  const int bid = blockIdx.x;
  {
    int g0 = bid * 256 + tid;
    if (g0 < N_T) u[g0] = A_VAL;
    if (g0 < 2) errAcc[g0] = 0.0f;
  }
  grid.sync();
  for (int t = 1; t <= 100; ++t) {
    const bool check = (t == 2) || (t == 52);
    for (int i = tid; i < N_T; i += 256) su[i] = u[i];
    __syncthreads();
    const int g = tid >> 5, jl = tid & 31;
    float eacc = 0.0f;
    for (int c = bid; c < NCHUNK; c += COOP_BLOCKS) {
      const int j0 = c * 64;
      const int jj = j0 + jl * 2;
      float p0 = 0.f, p1 = 0.f;
      if (jj < M_V) {
        const float* base = Km + (size_t)(g * 128) * M_V + jj;
        #pragma unroll 4
        for (int i = 0; i < 128; ++i) {
          float k0, k1;
          if (AL) {
            float2 kk = *(const float2*)(base + (size_t)i * M_V);
            k0 = kk.x; k1 = kk.y;
          } else {
            k0 = base[(size_t)i * M_V];
            k1 = base[(size_t)i * M_V + 1];
          }
          float uu = su[g * 128 + i];
          p0 += k0 * uu; p1 += k1 * uu;
        }
      }
      red[g][jl * 2]     = p0;
      red[g][jl * 2 + 1] = p1;
      __syncthreads();
      if (tid < 64) {
        int j = j0 + tid;
        if (j < M_V) {
          float st = 0.f;
          #pragma unroll
          for (int q = 0; q < 8; ++q) st += red[q][tid];
          if (check) {
            s[j] = st;
            eacc += fabsf(v[j] * st - B_VAL);
          } else {
            v[j] = B_VAL / (st + EPSV);
          }
        }
      }
      __syncthreads();
    }
    if (check) {
      float e = blockReduce256(eacc);
      if (tid == 0) atomicAdd(&errAcc[t == 2 ? 0 : 1], e);
    }
    grid.sync();
    if (check) {
      float e = errAcc[t == 2 ? 0 : 1];
      if (e <= THR) break;
      if (tid < 64) {
        for (int c = bid; c < NCHUNK; c += COOP_BLOCKS) {
          int j = c * 64 + tid;
          if (j < M_V) v[j] = B_VAL / (s[j] + EPSV);
        }
      }
      grid.sync();
    }
    {
      int i = bid;
      float p = 0.f;
      if (i < N_T) {
        const float* row = Km + (size_t)i * M_V;
        if (AL) {
          const float4* r4 = (const float4*)row;
          const float4* v4 = (const float4*)v;
          for (int j = tid; j < M_V / 4; j += 256) {
            float4 kk = r4[j]; float4 vv = v4[j];
            p += kk.x * vv.x + kk.y * vv.y + kk.z * vv.z + kk.w * vv.w;
          }
        } else {
          for (int j = tid; j < M_V; j += 256) p += row[j] * v[j];
        }
      }
      p = blockReduce256(p);
      if (tid == 0 && i < N_T) u[i] = A_VAL / (p + EPSV);
    }
    grid.sync();
  }
}

// ---- gated redo final (runs only if not converged at first check) ----
__global__ __launch_bounds__(256) void final_kernel(const float* Kmat,
                                                    const float* __restrict__ u,
                                                    const float* __restrict__ v,
                                                    float* out,
                                                    float* __restrict__ partials,
                                                    const int* __restrict__ gate) {
  if (*gate == 0) return;   // uniform per block; no syncthreads before this
  int j = blockIdx.x * 256 + threadIdx.x;
  float contrib = 0.0f;
  if (j < M_V) {
    float vj = v[j];
    #pragma unroll 4
    for (int r = 0; r < 16; ++r) {
      int i = blockIdx.y * 16 + r;
      size_t idx = (size_t)i * M_V + j;
      float k = Kmat[idx];
      float tr = u[i] * k * vj;
      float m = -__logf(k) * INV_ALPHA;
      out[1 + idx] = tr;
      contrib += tr * m;
    }
  }
  contrib = blockReduce256(contrib);
  if (threadIdx.x == 0) partials[blockIdx.y * gridDim.x + blockIdx.x] = contrib;
}

__global__ __launch_bounds__(256) void finish_kernel(const float* __restrict__ partials,
                                                     float* out, int np_,
                                                     const int* __restrict__ gate) {
  if (*gate == 0) return;
  float s = 0.0f;
  for (int i = threadIdx.x; i < np_; i += 256) s += partials[i];
  s = blockReduce256(s);
  if (threadIdx.x == 0) out[0] = s;
}

extern "C" void kernel_launch(void* const* d_in, const int* in_sizes, int n_in,
                              void* d_out, int out_size, void* d_ws, size_t ws_size,
                              hipStream_t stream) {
  const float* x = (const float*)d_in[0];
  const float* y = (const float*)d_in[1];
  float* out = (float*)d_out;

  uintptr_t wp = (uintptr_t)d_ws;
  uintptr_t wend = (uintptr_t)d_ws + ws_size;
  auto alloc = [&](size_t bytes) -> void* {
    wp = (wp + 255) & ~(uintptr_t)255;
    void* p = (void*)wp;
    wp += bytes;
    return p;
  };
  float* u        = (float*)alloc((size_t)N_T * 4);
  float* v        = (float*)alloc((size_t)M_V * 4);
  float* s        = (float*)alloc((size_t)M_V * 4);
  float* xx       = (float*)alloc((size_t)N_T * 4);
  float* yy       = (float*)alloc((size_t)M_V * 4);
  float* partials = (float*)alloc((size_t)NPART * 4);
  float* lossPart = (float*)alloc((size_t)LPART * 4);
  float* rowPart  = (float*)alloc((size_t)4 * N_T * 4);
  float* errAcc   = (float*)alloc(64);
  int*   notconv  = (int*)alloc(64);
  float* colsumPart = (float*)alloc((size_t)16 * NPAD * 4);

  const size_t apbytes = (size_t)N_T * KPACK * 2;
  const size_t bpbytes = (size_t)NPAD * KPACK * 2;
  const size_t kbytes  = (size_t)N_T * M_V * 4;

  bool mfma_path = ((wp + 511) + apbytes + bpbytes) <= wend;
  unsigned short* Ap = nullptr;
  unsigned short* Bp = nullptr;
  if (mfma_path) {
    Ap = (unsigned short*)alloc(apbytes);
    Bp = (unsigned short*)alloc(bpbytes);
  }
  bool k_in_ws = ((wp + 511) + kbytes) <= wend;
  float* Kmat = k_in_ws ? (float*)alloc(kbytes) : out + 1;
  // sPart (12.8 MB) aliases Bp (76.9 MB) — Bp is dead after the GEMM.
  float* sPart = (float*)Bp;

  sumsq_kernel<<<N_T, 256, 0, stream>>>(x, xx, N_T);
  sumsq_kernel<<<M_V, 256, 0, stream>>>(y, yy, M_V);

  if (mfma_path && k_in_ws) {
    // ---- fast path ----
    pack_x_kernel<<<N_T / 2, 256, 0, stream>>>(x, Ap);
    pack_y_kernel<<<NPAD / 2, 256, 0, stream>>>(y, Bp);
    dim3 ggrid((M_V + 127) / 128, N_T / 128);
    mfma_gemm_kernel<<<ggrid, 256, 0, stream>>>(Ap, Bp, xx, yy, Kmat, colsumPart);

    v1_kernel<<<CBLK, 256, 0, stream>>>(colsumPart, v, errAcc);
    rowpass_kernel<<<dim3(4, N_T), 256, 0, stream>>>(Kmat, v, rowPart);
    u_kernel<<<N_T / 256, 256, 0, stream>>>(rowPart, u);

    specfinal_kernel<<<dim3(FBLK, 64), 256, 0, stream>>>(Kmat, u, v, out, sPart, lossPart);
    errfinish_kernel<<<CBLK, 256, 0, stream>>>(sPart, v, errAcc);
    setflag_kernel<<<1, 1, 0, stream>>>(errAcc, notconv);
    finishloss_kernel<<<1, 256, 0, stream>>>(lossPart, out, LPART);

    // safety net: only if err > THR at first check (gated, ~free when converged)
    void* coopArgs[] = {(void*)&Kmat, (void*)&u, (void*)&v, (void*)&s,
                        (void*)&errAcc, (void*)&notconv};
    hipLaunchCooperativeKernel(reinterpret_cast<void*>(sinkhorn_coop<true>),
                               dim3(COOP_BLOCKS), dim3(256), coopArgs, 0, stream);
    final_kernel<<<dim3(CBLK, 64), 256, 0, stream>>>(Kmat, u, v, out, partials, notconv);
    finish_kernel<<<1, 256, 0, stream>>>(partials, out, NPART, notconv);
  } else {
    // ---- fallback: round-2 flow ----
    if (mfma_path) {
      pack_x_kernel<<<N_T / 2, 256, 0, stream>>>(x, Ap);
      pack_y_kernel<<<NPAD / 2, 256, 0, stream>>>(y, Bp);
      dim3 ggrid((M_V + 127) / 128, N_T / 128);
      mfma_gemm_kernel<<<ggrid, 256, 0, stream>>>(Ap, Bp, xx, yy, Kmat, colsumPart);
    } else {
      dim3 ggrid((M_V + BN - 1) / BN, N_T / BM);
      gemm_k_kernel<<<ggrid, 256, 0, stream>>>(x, y, xx, yy, Kmat);
    }
    set1_kernel<<<1, 1, 0, stream>>>(notconv);
    void* coopArgs[] = {(void*)&Kmat, (void*)&u, (void*)&v, (void*)&s,
                        (void*)&errAcc, (void*)&notconv};
    if (k_in_ws) {
      hipLaunchCooperativeKernel(reinterpret_cast<void*>(sinkhorn_coop<true>),
                                 dim3(COOP_BLOCKS), dim3(256), coopArgs, 0, stream);
    } else {
      hipLaunchCooperativeKernel(reinterpret_cast<void*>(sinkhorn_coop<false>),
                                 dim3(COOP_BLOCKS), dim3(256), coopArgs, 0, stream);
    }
    final_kernel<<<dim3(CBLK, 64), 256, 0, stream>>>(Kmat, u, v, out, partials, notconv);
    finish_kernel<<<1, 256, 0, stream>>>(partials, out, NPART, notconv);
  }
}

// Round 4
// 347.805 us; speedup vs baseline: 3.2358x; 1.2025x over previous
//
#include <hip/hip_runtime.h>
#include <hip/hip_cooperative_groups.h>
#include <cstdint>

namespace cg = cooperative_groups;

#define N_T 1024
#define M_V 50000
#define DIMS 256
#define KPACK 768
#define NPAD 50048
#define CBLK 196            // ceil(50000/256)
#define NPART (CBLK * 64)
#define NCHUNK 782          // coop colpass chunks
#define COOP_BLOCKS 1024
#define J4TOT 12500         // 50000/4 columns-of-4
#define FBLK 49             // ceil(12500/256)
#define LPART (FBLK * 64)

constexpr float ALPHA     = 0.05f;
constexpr float INV_ALPHA = 20.0f;
constexpr float A_VAL     = 1.0f / 1024.0f;
constexpr float B_VAL     = 1.0f / 50000.0f;
constexpr float THR       = 0.005f;
constexpr float EPSV      = 1e-16f;

typedef short    bf16x8 __attribute__((ext_vector_type(8)));
typedef float    f32x4  __attribute__((ext_vector_type(4)));
typedef _Float16 half8v __attribute__((ext_vector_type(8)));
typedef _Float16 half4v __attribute__((ext_vector_type(4)));

__device__ __forceinline__ float blockReduce256(float val) {
  #pragma unroll
  for (int off = 32; off; off >>= 1) val += __shfl_down(val, off, 64);
  __shared__ float redw[4];
  int lane = threadIdx.x & 63;
  int wid  = threadIdx.x >> 6;
  if (lane == 0) redw[wid] = val;
  __syncthreads();
  float r = 0.0f;
  if (threadIdx.x == 0) r = redw[0] + redw[1] + redw[2] + redw[3];
  __syncthreads();
  return r;
}

__device__ __forceinline__ unsigned short f2bf(float f) {
  union { float f; unsigned u; } c{f};
  unsigned r = c.u + 0x7FFF + ((c.u >> 16) & 1);   // RNE
  return (unsigned short)(r >> 16);
}
__device__ __forceinline__ float bf2f(unsigned short b) {
  union { unsigned u; float f; } c{(unsigned)b << 16};
  return c.f;
}

__device__ __forceinline__ void gload16(const void* g, void* l) {
  __builtin_amdgcn_global_load_lds((const __attribute__((address_space(1))) unsigned int*)g,
                                   (__attribute__((address_space(3))) unsigned int*)l, 16, 0, 0);
}

// ---- row sum of squares ----
__global__ __launch_bounds__(256) void sumsq_kernel(const float* __restrict__ in,
                                                    float* __restrict__ o, int rows) {
  int r = blockIdx.x;
  if (r >= rows) return;
  float v = in[(size_t)r * DIMS + threadIdx.x];
  float s = blockReduce256(v * v);
  if (threadIdx.x == 0) o[r] = s;
}

// ---- pack x -> A' = [xh | xl | xh] ----
__global__ __launch_bounds__(256) void pack_x_kernel(const float* __restrict__ x,
                                                     unsigned short* __restrict__ Ap) {
  int r = blockIdx.x * 2 + (threadIdx.x >> 7);
  int k = (threadIdx.x & 127) * 2;
  float2 vx = *(const float2*)&x[(size_t)r * DIMS + k];
  ushort2 h2, l2;
  h2.x = f2bf(vx.x); h2.y = f2bf(vx.y);
  l2.x = f2bf(vx.x - bf2f(h2.x)); l2.y = f2bf(vx.y - bf2f(h2.y));
  *(ushort2*)&Ap[(size_t)r * KPACK + k]           = h2;
  *(ushort2*)&Ap[(size_t)r * KPACK + DIMS + k]    = l2;
  *(ushort2*)&Ap[(size_t)r * KPACK + 2*DIMS + k]  = h2;
}

// ---- pack y -> B' = [yh | yh | yl] ----
__global__ __launch_bounds__(256) void pack_y_kernel(const float* __restrict__ y,
                                                     unsigned short* __restrict__ Bp) {
  int r = blockIdx.x * 2 + (threadIdx.x >> 7);
  int k = (threadIdx.x & 127) * 2;
  ushort2 h2 = {0, 0}, l2 = {0, 0};
  if (r < M_V) {
    float2 vy = *(const float2*)&y[(size_t)r * DIMS + k];
    h2.x = f2bf(vy.x); h2.y = f2bf(vy.y);
    l2.x = f2bf(vy.x - bf2f(h2.x)); l2.y = f2bf(vy.y - bf2f(h2.y));
  }
  *(ushort2*)&Bp[(size_t)r * KPACK + k]          = h2;
  *(ushort2*)&Bp[(size_t)r * KPACK + DIMS + k]   = h2;
  *(ushort2*)&Bp[(size_t)r * KPACK + 2*DIMS + k] = l2;
}

// ---- MFMA GEMM -> f16 K + fused column-sum partials ----
// grid (8, 391): x = row-tile (fastest) so the 8 blocks sharing a Bp panel
// are dispatch-adjacent -> Bp HBM-fetched once, served from L3/L2 after.
__global__ __launch_bounds__(256) void mfma_gemm_kernel(const unsigned short* __restrict__ Ap,
                                                        const unsigned short* __restrict__ Bp,
                                                        const float* __restrict__ xx,
                                                        const float* __restrict__ yy,
                                                        _Float16* __restrict__ Kh,
                                                        float* __restrict__ colsumPart) {
  __shared__ unsigned short As[128][32];
  __shared__ unsigned short Bs[128][32];
  const int tid  = threadIdx.x;
  const int lane = tid & 63;
  const int wid  = tid >> 6;
  const int wr = wid >> 1, wc = wid & 1;
  const int i0 = blockIdx.x * 128;   // row tile
  const int j0 = blockIdx.y * 128;   // col panel

  f32x4 acc[4][4];
  #pragma unroll
  for (int m = 0; m < 4; ++m)
    #pragma unroll
    for (int n = 0; n < 4; ++n) acc[m][n] = (f32x4){0.f, 0.f, 0.f, 0.f};

  const int srow   = lane >> 2;
  const int schunk = lane & 3;

  for (int k0 = 0; k0 < KPACK; k0 += 32) {
    #pragma unroll
    for (int q = 0; q < 2; ++q) {
      int rbase = (wid * 2 + q) * 16;
      int row = rbase + srow;
      int cg_ = schunk ^ ((row ^ (row >> 2)) & 3);
      gload16(Ap + (size_t)(i0 + row) * KPACK + k0 + cg_ * 8, &As[rbase][0]);
      gload16(Bp + (size_t)(j0 + row) * KPACK + k0 + cg_ * 8, &Bs[rbase][0]);
    }
    __syncthreads();
    bf16x8 af[4], bfr[4];
    #pragma unroll
    for (int m = 0; m < 4; ++m) {
      int row = wr * 64 + m * 16 + (lane & 15);
      int ch  = (lane >> 4) ^ ((row ^ (row >> 2)) & 3);
      af[m] = *(const bf16x8*)&As[row][ch * 8];
    }
    #pragma unroll
    for (int n = 0; n < 4; ++n) {
      int col = wc * 64 + n * 16 + (lane & 15);
      int ch  = (lane >> 4) ^ ((col ^ (col >> 2)) & 3);
      bfr[n] = *(const bf16x8*)&Bs[col][ch * 8];
    }
    #pragma unroll
    for (int m = 0; m < 4; ++m)
      #pragma unroll
      for (int n = 0; n < 4; ++n)
        acc[m][n] = __builtin_amdgcn_mfma_f32_16x16x32_bf16(af[m], bfr[n], acc[m][n], 0, 0, 0);
    __syncthreads();
  }

  // epilogue: D col=lane&15, row=(lane>>4)*4+reg; f16 store; colsum of the
  // ROUNDED values so every downstream consumer sees a consistent K.
  float csum[4] = {0.f, 0.f, 0.f, 0.f};
  #pragma unroll
  for (int m = 0; m < 4; ++m) {
    int rowb = i0 + wr * 64 + m * 16 + (lane >> 4) * 4;
    #pragma unroll
    for (int n = 0; n < 4; ++n) {
      int col = j0 + wc * 64 + n * 16 + (lane & 15);
      float yyc = (col < M_V) ? yy[col] : 0.0f;
      #pragma unroll
      for (int r = 0; r < 4; ++r) {
        float mval = xx[rowb + r] + yyc - 2.0f * acc[m][n][r];
        _Float16 kh = (_Float16)__expf(-ALPHA * mval);
        if (col < M_V) Kh[(size_t)(rowb + r) * M_V + col] = kh;
        csum[n] += (float)kh;
      }
    }
  }
  #pragma unroll
  for (int n = 0; n < 4; ++n) {
    float c = csum[n];
    c += __shfl_xor(c, 16, 64);
    c += __shfl_xor(c, 32, 64);
    if (lane < 16) {
      int col = j0 + wc * 64 + n * 16 + lane;
      colsumPart[(size_t)(blockIdx.x * 2 + wr) * NPAD + col] = c;
    }
  }
}

// ---- fallback f32 GEMM (only if ws too small; writes f32 K) ----
#define BM 64
#define BN 64
#define BK 32
__global__ __launch_bounds__(256) void gemm_k_kernel(const float* __restrict__ x,
                                                     const float* __restrict__ y,
                                                     const float* __restrict__ xx,
                                                     const float* __restrict__ yy,
                                                     float* Kmat) {
  __shared__ float As[BK][BM];
  __shared__ float Bs[BK][BN + 1];
  int tid = threadIdx.x;
  int i0 = blockIdx.y * BM;
  int j0 = blockIdx.x * BN;
  int tx = tid & 15, ty = tid >> 4;
  float acc[4][4] = {};
  for (int k0 = 0; k0 < DIMS; k0 += BK) {
    #pragma unroll
    for (int l = tid; l < 512; l += 256) {
      int r = l >> 3, kq = l & 7;
      float4 a4 = *(const float4*)&x[(size_t)(i0 + r) * DIMS + k0 + kq * 4];
      As[kq * 4 + 0][r] = a4.x; As[kq * 4 + 1][r] = a4.y;
      As[kq * 4 + 2][r] = a4.z; As[kq * 4 + 3][r] = a4.w;
    }
    #pragma unroll
    for (int l = tid; l < 512; l += 256) {
      int r = l >> 3, kq = l & 7;
      int j = j0 + r;
      float4 b4 = make_float4(0.f, 0.f, 0.f, 0.f);
      if (j < M_V) b4 = *(const float4*)&y[(size_t)j * DIMS + k0 + kq * 4];
      Bs[kq * 4 + 0][r] = b4.x; Bs[kq * 4 + 1][r] = b4.y;
      Bs[kq * 4 + 2][r] = b4.z; Bs[kq * 4 + 3][r] = b4.w;
    }
    __syncthreads();
    #pragma unroll
    for (int k = 0; k < BK; ++k) {
      float a[4], b[4];
      #pragma unroll
      for (int r = 0; r < 4; ++r) a[r] = As[k][ty * 4 + r];
      #pragma unroll
      for (int c = 0; c < 4; ++c) b[c] = Bs[k][tx * 4 + c];
      #pragma unroll
      for (int r = 0; r < 4; ++r)
        #pragma unroll
        for (int c = 0; c < 4; ++c) acc[r][c] += a[r] * b[c];
    }
    __syncthreads();
  }
  #pragma unroll
  for (int r = 0; r < 4; ++r) {
    int i = i0 + ty * 4 + r;
    float xxi = xx[i];
    #pragma unroll
    for (int c = 0; c < 4; ++c) {
      int j = j0 + tx * 4 + c;
      if (j < M_V) {
        float m = xxi + yy[j] - 2.0f * acc[r][c];
        Kmat[(size_t)i * M_V + j] = __expf(-ALPHA * m);
      }
    }
  }
}

// ---- v1: v_j = b / (colsum_j * a + eps); zero errAcc ----
__global__ __launch_bounds__(256) void v1_kernel(const float* __restrict__ cp,
                                                 float* __restrict__ v,
                                                 float* __restrict__ errAcc) {
  int j = blockIdx.x * 256 + threadIdx.x;
  if (j == 0) errAcc[0] = 0.0f;
  if (j < M_V) {
    float s = 0.0f;
    #pragma unroll
    for (int q = 0; q < 16; ++q) s += cp[(size_t)q * NPAD + j];
    v[j] = B_VAL / (s * A_VAL + EPSV);
  }
}

// ---- rowpass on f16 K: grid (2, N_T), 25000 halves per chunk ----
__global__ __launch_bounds__(256) void rowpass_kernel(const _Float16* __restrict__ Kh,
                                                      const float* __restrict__ v,
                                                      float* __restrict__ rowPart) {
  const int i = blockIdx.y;
  const int c = blockIdx.x;  // 0 or 1
  const half8v* K8 = (const half8v*)(Kh + (size_t)i * M_V);
  const float4* v4 = (const float4*)v;
  float p = 0.0f;
  int q = c * 3125 + threadIdx.x;
  #pragma unroll
  for (int it = 0; it < 12; ++it, q += 256) {
    half8v k8 = K8[q];
    float4 va = v4[q * 2], vb = v4[q * 2 + 1];
    p += (float)k8[0] * va.x + (float)k8[1] * va.y + (float)k8[2] * va.z + (float)k8[3] * va.w
       + (float)k8[4] * vb.x + (float)k8[5] * vb.y + (float)k8[6] * vb.z + (float)k8[7] * vb.w;
  }
  if (threadIdx.x < 53) {
    int q2 = c * 3125 + 3072 + threadIdx.x;
    half8v k8 = K8[q2];
    float4 va = v4[q2 * 2], vb = v4[q2 * 2 + 1];
    p += (float)k8[0] * va.x + (float)k8[1] * va.y + (float)k8[2] * va.z + (float)k8[3] * va.w
       + (float)k8[4] * vb.x + (float)k8[5] * vb.y + (float)k8[6] * vb.z + (float)k8[7] * vb.w;
  }
  p = blockReduce256(p);
  if (threadIdx.x == 0) rowPart[c * N_T + i] = p;
}

__global__ void u_kernel(const float* __restrict__ rowPart, float* __restrict__ u) {
  int i = blockIdx.x * 256 + threadIdx.x;
  u[i] = A_VAL / (rowPart[i] + rowPart[N_T + i] + EPSV);
}

// ---- speculative final: transp (f32 out) + loss partials + s=K^T u partials ----
__global__ __launch_bounds__(256) void specfinal_kernel(const _Float16* __restrict__ Kh,
                                                        const float* __restrict__ u_,
                                                        const float* __restrict__ v_,
                                                        float* __restrict__ out,
                                                        float* __restrict__ sPart,
                                                        float* __restrict__ lossPart) {
  const int j4 = blockIdx.x * 256 + threadIdx.x;
  const int by = blockIdx.y;
  float contrib = 0.0f;
  if (j4 < J4TOT) {
    float4 vv = ((const float4*)v_)[j4];
    float4 sp = {0.f, 0.f, 0.f, 0.f};
    const size_t jb = (size_t)j4 * 4;
    #pragma unroll
    for (int r = 0; r < 16; ++r) {
      int i = by * 16 + r;
      half4v k4 = *(const half4v*)(Kh + (size_t)i * M_V + jb);
      float kx = (float)k4[0], ky = (float)k4[1], kz = (float)k4[2], kw = (float)k4[3];
      float ui = u_[i];
      float tx_ = ui * kx * vv.x, ty_ = ui * ky * vv.y;
      float tz_ = ui * kz * vv.z, tw_ = ui * kw * vv.w;
      size_t o = 1 + (size_t)i * M_V + jb;
      out[o] = tx_; out[o + 1] = ty_; out[o + 2] = tz_; out[o + 3] = tw_;
      contrib += tx_ * (-__logf(kx)) + ty_ * (-__logf(ky))
               + tz_ * (-__logf(kz)) + tw_ * (-__logf(kw));
      sp.x += kx * ui; sp.y += ky * ui; sp.z += kz * ui; sp.w += kw * ui;
    }
    ((float4*)(sPart + (size_t)by * M_V))[j4] = sp;
  }
  contrib = blockReduce256(contrib) * INV_ALPHA;
  if (threadIdx.x == 0) lossPart[by * FBLK + blockIdx.x] = contrib;
}

// ---- err = sum_j |v_j * s_j - b| ----
__global__ __launch_bounds__(256) void errfinish_kernel(const float* __restrict__ sPart,
                                                        const float* __restrict__ v_,
                                                        float* errAcc) {
  int j = blockIdx.x * 256 + threadIdx.x;
  float e = 0.0f;
  if (j < M_V) {
    float s = 0.0f;
    #pragma unroll
    for (int q = 0; q < 64; ++q) s += sPart[(size_t)q * M_V + j];
    e = fabsf(v_[j] * s - B_VAL);
  }
  e = blockReduce256(e);
  if (threadIdx.x == 0) atomicAdd(errAcc, e);
}

__global__ void setflag_kernel(const float* errAcc, int* notconv) {
  *notconv = (errAcc[0] > THR) ? 1 : 0;
}
__global__ void set1_kernel(int* p) { *p = 1; }

__global__ __launch_bounds__(256) void finishloss_kernel(const float* __restrict__ lossPart,
                                                         float* out, int np_) {
  float s = 0.0f;
  for (int i = threadIdx.x; i < np_; i += 256) s += lossPart[i];
  s = blockReduce256(s);
  if (threadIdx.x == 0) out[0] = s;
}

// ---- safety-net cooperative Sinkhorn (gated; scalar loads, perf-irrelevant) ----
template <typename KT>
__global__ __launch_bounds__(256, 4) void sinkhorn_coop(const KT* Km,
                                                        float* __restrict__ u,
                                                        float* __restrict__ v,
                                                        float* __restrict__ s,
                                                        float* __restrict__ errAcc,
                                                        const int* __restrict__ notconv) {
  if (*notconv == 0) return;   // uniform across grid
  cg::grid_group grid = cg::this_grid();
  __shared__ float su[N_T];
  __shared__ float red[8][64];
  const int tid = threadIdx.x;
  const int bid = blockIdx.x;
  {
    int g0 = bid * 256 + tid;
    if (g0 < N_T) u[g0] = A_VAL;
    if (g0 < 2) errAcc[g0] = 0.0f;
  }
  grid.sync();
  for (int t = 1; t <= 100; ++t) {
    const bool check = (t == 2) || (t == 52);
    for (int i = tid; i < N_T; i += 256) su[i] = u[i];
    __syncthreads();
    const int g = tid >> 5, jl = tid & 31;
    float eacc = 0.0f;
    for (int c = bid; c < NCHUNK; c += COOP_BLOCKS) {
      const int j0 = c * 64;
      const int jj = j0 + jl * 2;
      float p0 = 0.f, p1 = 0.f;
      if (jj < M_V) {
        const KT* base = Km + (size_t)(g * 128) * M_V + jj;
        #pragma unroll 4
        for (int i = 0; i < 128; ++i) {
          float k0 = (float)base[(size_t)i * M_V];
          float k1 = (float)base[(size_t)i * M_V + 1];
          float uu = su[g * 128 + i];
          p0 += k0 * uu; p1 += k1 * uu;
        }
      }
      red[g][jl * 2]     = p0;
      red[g][jl * 2 + 1] = p1;
      __syncthreads();
      if (tid < 64) {
        int j = j0 + tid;
        if (j < M_V) {
          float st = 0.f;
          #pragma unroll
          for (int q = 0; q < 8; ++q) st += red[q][tid];
          if (check) {
            s[j] = st;
            eacc += fabsf(v[j] * st - B_VAL);
          } else {
            v[j] = B_VAL / (st + EPSV);
          }
        }
      }
      __syncthreads();
    }
    if (check) {
      float e = blockReduce256(eacc);
      if (tid == 0) atomicAdd(&errAcc[t == 2 ? 0 : 1], e);
    }
    grid.sync();
    if (check) {
      float e = errAcc[t == 2 ? 0 : 1];
      if (e <= THR) break;
      if (tid < 64) {
        for (int c = bid; c < NCHUNK; c += COOP_BLOCKS) {
          int j = c * 64 + tid;
          if (j < M_V) v[j] = B_VAL / (s[j] + EPSV);
        }
      }
      grid.sync();
    }
    {
      int i = bid;
      float p = 0.f;
      if (i < N_T) {
        const KT* row = Km + (size_t)i * M_V;
        for (int j = tid; j < M_V; j += 256) p += (float)row[j] * v[j];
      }
      p = blockReduce256(p);
      if (tid == 0 && i < N_T) u[i] = A_VAL / (p + EPSV);
    }
    grid.sync();
  }
}

// ---- gated redo final ----
template <typename KT>
__global__ __launch_bounds__(256) void final_kernel(const KT* Kmat,
                                                    const float* __restrict__ u,
                                                    const float* __restrict__ v,
                                                    float* out,
                                                    float* __restrict__ partials,
                                                    const int* __restrict__ gate) {
  if (*gate == 0) return;
  int j = blockIdx.x * 256 + threadIdx.x;
  float contrib = 0.0f;
  if (j < M_V) {
    float vj = v[j];
    #pragma unroll 4
    for (int r = 0; r < 16; ++r) {
      int i = blockIdx.y * 16 + r;
      size_t idx = (size_t)i * M_V + j;
      float k = (float)Kmat[idx];
      float tr = u[i] * k * vj;
      float m = -__logf(k) * INV_ALPHA;
      out[1 + idx] = tr;
      contrib += tr * m;
    }
  }
  contrib = blockReduce256(contrib);
  if (threadIdx.x == 0) partials[blockIdx.y * gridDim.x + blockIdx.x] = contrib;
}

__global__ __launch_bounds__(256) void finish_kernel(const float* __restrict__ partials,
                                                     float* out, int np_,
                                                     const int* __restrict__ gate) {
  if (*gate == 0) return;
  float s = 0.0f;
  for (int i = threadIdx.x; i < np_; i += 256) s += partials[i];
  s = blockReduce256(s);
  if (threadIdx.x == 0) out[0] = s;
}

extern "C" void kernel_launch(void* const* d_in, const int* in_sizes, int n_in,
                              void* d_out, int out_size, void* d_ws, size_t ws_size,
                              hipStream_t stream) {
  const float* x = (const float*)d_in[0];
  const float* y = (const float*)d_in[1];
  float* out = (float*)d_out;

  uintptr_t wp = (uintptr_t)d_ws;
  uintptr_t wend = (uintptr_t)d_ws + ws_size;
  auto alloc = [&](size_t bytes) -> void* {
    wp = (wp + 255) & ~(uintptr_t)255;
    void* p = (void*)wp;
    wp += bytes;
    return p;
  };
  float* u        = (float*)alloc((size_t)N_T * 4);
  float* v        = (float*)alloc((size_t)M_V * 4);
  float* s        = (float*)alloc((size_t)M_V * 4);
  float* xx       = (float*)alloc((size_t)N_T * 4);
  float* yy       = (float*)alloc((size_t)M_V * 4);
  float* partials = (float*)alloc((size_t)NPART * 4);
  float* lossPart = (float*)alloc((size_t)LPART * 4);
  float* rowPart  = (float*)alloc((size_t)2 * N_T * 4);
  float* errAcc   = (float*)alloc(64);
  int*   notconv  = (int*)alloc(64);
  float* colsumPart = (float*)alloc((size_t)16 * NPAD * 4);

  const size_t apbytes = (size_t)N_T * KPACK * 2;
  const size_t bpbytes = (size_t)NPAD * KPACK * 2;
  const size_t khbytes = (size_t)N_T * M_V * 2;   // f16 K
  const size_t kfbytes = (size_t)N_T * M_V * 4;   // f32 K (fallback)

  bool fast = ((wp + 1024) + apbytes + bpbytes + khbytes) <= wend;

  sumsq_kernel<<<N_T, 256, 0, stream>>>(x, xx, N_T);
  sumsq_kernel<<<M_V, 256, 0, stream>>>(y, yy, M_V);

  if (fast) {
    unsigned short* Ap = (unsigned short*)alloc(apbytes);
    unsigned short* Bp = (unsigned short*)alloc(bpbytes);
    _Float16*       Kh = (_Float16*)alloc(khbytes);
    float* sPart = (float*)Bp;   // Bp dead after GEMM; sPart 12.8MB < 76.9MB

    pack_x_kernel<<<N_T / 2, 256, 0, stream>>>(x, Ap);
    pack_y_kernel<<<NPAD / 2, 256, 0, stream>>>(y, Bp);
    mfma_gemm_kernel<<<dim3(N_T / 128, (M_V + 127) / 128), 256, 0, stream>>>(
        Ap, Bp, xx, yy, Kh, colsumPart);

    v1_kernel<<<CBLK, 256, 0, stream>>>(colsumPart, v, errAcc);
    rowpass_kernel<<<dim3(2, N_T), 256, 0, stream>>>(Kh, v, rowPart);
    u_kernel<<<N_T / 256, 256, 0, stream>>>(rowPart, u);

    specfinal_kernel<<<dim3(FBLK, 64), 256, 0, stream>>>(Kh, u, v, out, sPart, lossPart);
    errfinish_kernel<<<CBLK, 256, 0, stream>>>(sPart, v, errAcc);
    setflag_kernel<<<1, 1, 0, stream>>>(errAcc, notconv);
    finishloss_kernel<<<1, 256, 0, stream>>>(lossPart, out, LPART);

    // safety net (gated off when converged at first check)
    void* coopArgs[] = {(void*)&Kh, (void*)&u, (void*)&v, (void*)&s,
                        (void*)&errAcc, (void*)&notconv};
    hipLaunchCooperativeKernel(reinterpret_cast<void*>(sinkhorn_coop<_Float16>),
                               dim3(COOP_BLOCKS), dim3(256), coopArgs, 0, stream);
    final_kernel<_Float16><<<dim3(CBLK, 64), 256, 0, stream>>>(Kh, u, v, out, partials, notconv);
    finish_kernel<<<1, 256, 0, stream>>>(partials, out, NPART, notconv);
  } else {
    // fallback: f32 K (in ws if it fits, else in out+1), full coop loop
    bool k_in_ws = ((wp + 512) + kfbytes) <= wend;
    float* Kmat = k_in_ws ? (float*)alloc(kfbytes) : out + 1;
    gemm_k_kernel<<<dim3((M_V + BN - 1) / BN, N_T / BM), 256, 0, stream>>>(x, y, xx, yy, Kmat);
    set1_kernel<<<1, 1, 0, stream>>>(notconv);
    void* coopArgs[] = {(void*)&Kmat, (void*)&u, (void*)&v, (void*)&s,
                        (void*)&errAcc, (void*)&notconv};
    hipLaunchCooperativeKernel(reinterpret_cast<void*>(sinkhorn_coop<float>),
                               dim3(COOP_BLOCKS), dim3(256), coopArgs, 0, stream);
    final_kernel<float><<<dim3(CBLK, 64), 256, 0, stream>>>(Kmat, u, v, out, partials, notconv);
    finish_kernel<<<1, 256, 0, stream>>>(partials, out, NPART, notconv);
  }
}

// Round 5
// 305.166 us; speedup vs baseline: 3.6880x; 1.1397x over previous
//
#include <hip/hip_runtime.h>
#include <hip/hip_cooperative_groups.h>
#include <cstdint>

namespace cg = cooperative_groups;

#define N_T 1024
#define M_V 50000
#define DIMS 256
#define NPAD 50048
#define GPANELS 391         // 50048 / 128
#define CBLK 196            // ceil(50000/256)
#define NPART (CBLK * 64)
#define NCHUNK 782          // coop colpass chunks
#define COOP_BLOCKS 1024
#define J4TOT 12500         // 50000/4 columns-of-4
#define FBLK 49             // ceil(12500/256)
#define LPART (FBLK * 64)

constexpr float ALPHA     = 0.05f;
constexpr float INV_ALPHA = 20.0f;
constexpr float A_VAL     = 1.0f / 1024.0f;
constexpr float B_VAL     = 1.0f / 50000.0f;
constexpr float THR       = 0.005f;
constexpr float EPSV      = 1e-16f;

typedef short    bf16x8 __attribute__((ext_vector_type(8)));
typedef float    f32x4  __attribute__((ext_vector_type(4)));
typedef _Float16 half8v __attribute__((ext_vector_type(8)));
typedef _Float16 half4v __attribute__((ext_vector_type(4)));

__device__ __forceinline__ float blockReduce256(float val) {
  #pragma unroll
  for (int off = 32; off; off >>= 1) val += __shfl_down(val, off, 64);
  __shared__ float redw[4];
  int lane = threadIdx.x & 63;
  int wid  = threadIdx.x >> 6;
  if (lane == 0) redw[wid] = val;
  __syncthreads();
  float r = 0.0f;
  if (threadIdx.x == 0) r = redw[0] + redw[1] + redw[2] + redw[3];
  __syncthreads();
  return r;
}

__device__ __forceinline__ unsigned short f2bf(float f) {
  union { float f; unsigned u; } c{f};
  unsigned r = c.u + 0x7FFF + ((c.u >> 16) & 1);   // RNE
  return (unsigned short)(r >> 16);
}
__device__ __forceinline__ float bf2f(unsigned short b) {
  union { unsigned u; float f; } c{(unsigned)b << 16};
  return c.f;
}

__device__ __forceinline__ void gload16(const void* g, void* l) {
  __builtin_amdgcn_global_load_lds((const __attribute__((address_space(1))) unsigned int*)g,
                                   (__attribute__((address_space(3))) unsigned int*)l, 16, 0, 0);
}

// ---- row sum of squares ----
__global__ __launch_bounds__(256) void sumsq_kernel(const float* __restrict__ in,
                                                    float* __restrict__ o, int rows) {
  int r = blockIdx.x;
  if (r >= rows) return;
  float v = in[(size_t)r * DIMS + threadIdx.x];
  float s = blockReduce256(v * v);
  if (threadIdx.x == 0) o[r] = s;
}

// ---- pack x -> A' = [xh | xl]  (K=512) ----
__global__ __launch_bounds__(256) void pack_x_kernel(const float* __restrict__ x,
                                                     unsigned short* __restrict__ Ap) {
  int r = blockIdx.x * 2 + (threadIdx.x >> 7);
  int k = (threadIdx.x & 127) * 2;
  float2 vx = *(const float2*)&x[(size_t)r * DIMS + k];
  ushort2 h2, l2;
  h2.x = f2bf(vx.x); h2.y = f2bf(vx.y);
  l2.x = f2bf(vx.x - bf2f(h2.x)); l2.y = f2bf(vx.y - bf2f(h2.y));
  *(ushort2*)&Ap[(size_t)r * 512 + k]       = h2;
  *(ushort2*)&Ap[(size_t)r * 512 + 256 + k] = l2;
}

// ---- pack y -> B' = [yh]  (K=256), rows >= 50000 zero-padded ----
__global__ __launch_bounds__(256) void pack_y_kernel(const float* __restrict__ y,
                                                     unsigned short* __restrict__ Bp) {
  int r = blockIdx.x * 2 + (threadIdx.x >> 7);
  int k = (threadIdx.x & 127) * 2;
  ushort2 h2 = {0, 0};
  if (r < M_V) {
    float2 vy = *(const float2*)&y[(size_t)r * DIMS + k];
    h2.x = f2bf(vy.x); h2.y = f2bf(vy.y);
  }
  *(ushort2*)&Bp[(size_t)r * 256 + k] = h2;
}

// ---- MFMA GEMM -> f16 K + fused column-sum partials ----
// 1-D grid of 3136; XCD-aware mapping: the 8 row-tiles of a column panel get
// linear ids congruent mod 8 -> same XCD -> panel fetched into one L2 once.
// A = [xh|xl] (512), B = yh (256): acc = xh.yh + xl.yh (xh.yl term dropped;
// error ~N(0,0.009) in M, same order as f16-K rounding).
__global__ __launch_bounds__(256) void mfma_gemm_kernel(const unsigned short* __restrict__ Ap,
                                                        const unsigned short* __restrict__ Bp,
                                                        const float* __restrict__ xx,
                                                        const float* __restrict__ yy,
                                                        _Float16* __restrict__ Kh,
                                                        float* __restrict__ colsumPart) {
  const int t  = blockIdx.x & 63;
  const int gb = blockIdx.x >> 6;
  const int panel = gb * 8 + (t & 7);
  const int rt    = t >> 3;
  if (panel >= GPANELS) return;
  const int i0 = rt * 128;
  const int j0 = panel * 128;

  __shared__ unsigned short Ah[128][32];
  __shared__ unsigned short Al[128][32];
  __shared__ unsigned short Bs[128][32];
  const int tid  = threadIdx.x;
  const int lane = tid & 63;
  const int wid  = tid >> 6;
  const int wr = wid >> 1, wc = wid & 1;

  f32x4 acc[4][4];
  #pragma unroll
  for (int m = 0; m < 4; ++m)
    #pragma unroll
    for (int n = 0; n < 4; ++n) acc[m][n] = (f32x4){0.f, 0.f, 0.f, 0.f};

  const int srow  = lane >> 2;
  const int sslot = lane & 3;

  for (int k0 = 0; k0 < 256; k0 += 32) {
    #pragma unroll
    for (int q = 0; q < 2; ++q) {
      int rbase = (wid * 2 + q) * 16;
      int row = rbase + srow;
      int cg_ = sslot ^ ((row >> 1) & 3);
      gload16(Ap + (size_t)(i0 + row) * 512 + k0 + cg_ * 8,       &Ah[rbase][0]);
      gload16(Ap + (size_t)(i0 + row) * 512 + 256 + k0 + cg_ * 8, &Al[rbase][0]);
      gload16(Bp + (size_t)(j0 + row) * 256 + k0 + cg_ * 8,       &Bs[rbase][0]);
    }
    __syncthreads();
    bf16x8 ah[4], al[4], bb[4];
    #pragma unroll
    for (int m = 0; m < 4; ++m) {
      int row = wr * 64 + m * 16 + (lane & 15);
      int sl  = (lane >> 4) ^ ((row >> 1) & 3);
      ah[m] = *(const bf16x8*)&Ah[row][sl * 8];
      al[m] = *(const bf16x8*)&Al[row][sl * 8];
    }
    #pragma unroll
    for (int n = 0; n < 4; ++n) {
      int col = wc * 64 + n * 16 + (lane & 15);
      int sl  = (lane >> 4) ^ ((col >> 1) & 3);
      bb[n] = *(const bf16x8*)&Bs[col][sl * 8];
    }
    #pragma unroll
    for (int m = 0; m < 4; ++m)
      #pragma unroll
      for (int n = 0; n < 4; ++n) {
        acc[m][n] = __builtin_amdgcn_mfma_f32_16x16x32_bf16(ah[m], bb[n], acc[m][n], 0, 0, 0);
        acc[m][n] = __builtin_amdgcn_mfma_f32_16x16x32_bf16(al[m], bb[n], acc[m][n], 0, 0, 0);
      }
    __syncthreads();
  }

  // epilogue: D col=lane&15, row=(lane>>4)*4+reg; f16 store; colsum of ROUNDED values
  float csum[4] = {0.f, 0.f, 0.f, 0.f};
  #pragma unroll
  for (int m = 0; m < 4; ++m) {
    int rowb = i0 + wr * 64 + m * 16 + (lane >> 4) * 4;
    #pragma unroll
    for (int n = 0; n < 4; ++n) {
      int col = j0 + wc * 64 + n * 16 + (lane & 15);
      float yyc = (col < M_V) ? yy[col] : 0.0f;
      #pragma unroll
      for (int r = 0; r < 4; ++r) {
        float mval = xx[rowb + r] + yyc - 2.0f * acc[m][n][r];
        _Float16 kh = (_Float16)__expf(-ALPHA * mval);
        if (col < M_V) Kh[(size_t)(rowb + r) * M_V + col] = kh;
        csum[n] += (float)kh;
      }
    }
  }
  #pragma unroll
  for (int n = 0; n < 4; ++n) {
    float c = csum[n];
    c += __shfl_xor(c, 16, 64);
    c += __shfl_xor(c, 32, 64);
    if (lane < 16) {
      int col = j0 + wc * 64 + n * 16 + lane;
      colsumPart[(size_t)(rt * 2 + wr) * NPAD + col] = c;
    }
  }
}

// ---- fallback f32 GEMM (exact; only if ws too small) ----
#define BM 64
#define BN 64
#define BK 32
__global__ __launch_bounds__(256) void gemm_k_kernel(const float* __restrict__ x,
                                                     const float* __restrict__ y,
                                                     const float* __restrict__ xx,
                                                     const float* __restrict__ yy,
                                                     float* Kmat) {
  __shared__ float As[BK][BM];
  __shared__ float Bs[BK][BN + 1];
  int tid = threadIdx.x;
  int i0 = blockIdx.y * BM;
  int j0 = blockIdx.x * BN;
  int tx = tid & 15, ty = tid >> 4;
  float acc[4][4] = {};
  for (int k0 = 0; k0 < DIMS; k0 += BK) {
    #pragma unroll
    for (int l = tid; l < 512; l += 256) {
      int r = l >> 3, kq = l & 7;
      float4 a4 = *(const float4*)&x[(size_t)(i0 + r) * DIMS + k0 + kq * 4];
      As[kq * 4 + 0][r] = a4.x; As[kq * 4 + 1][r] = a4.y;
      As[kq * 4 + 2][r] = a4.z; As[kq * 4 + 3][r] = a4.w;
    }
    #pragma unroll
    for (int l = tid; l < 512; l += 256) {
      int r = l >> 3, kq = l & 7;
      int j = j0 + r;
      float4 b4 = make_float4(0.f, 0.f, 0.f, 0.f);
      if (j < M_V) b4 = *(const float4*)&y[(size_t)j * DIMS + k0 + kq * 4];
      Bs[kq * 4 + 0][r] = b4.x; Bs[kq * 4 + 1][r] = b4.y;
      Bs[kq * 4 + 2][r] = b4.z; Bs[kq * 4 + 3][r] = b4.w;
    }
    __syncthreads();
    #pragma unroll
    for (int k = 0; k < BK; ++k) {
      float a[4], b[4];
      #pragma unroll
      for (int r = 0; r < 4; ++r) a[r] = As[k][ty * 4 + r];
      #pragma unroll
      for (int c = 0; c < 4; ++c) b[c] = Bs[k][tx * 4 + c];
      #pragma unroll
      for (int r = 0; r < 4; ++r)
        #pragma unroll
        for (int c = 0; c < 4; ++c) acc[r][c] += a[r] * b[c];
    }
    __syncthreads();
  }
  #pragma unroll
  for (int r = 0; r < 4; ++r) {
    int i = i0 + ty * 4 + r;
    float xxi = xx[i];
    #pragma unroll
    for (int c = 0; c < 4; ++c) {
      int j = j0 + tx * 4 + c;
      if (j < M_V) {
        float m = xxi + yy[j] - 2.0f * acc[r][c];
        Kmat[(size_t)i * M_V + j] = __expf(-ALPHA * m);
      }
    }
  }
}

// ---- v1: v_j = b / (colsum_j * a + eps); zero errAcc ----
__global__ __launch_bounds__(256) void v1_kernel(const float* __restrict__ cp,
                                                 float* __restrict__ v,
                                                 float* __restrict__ errAcc) {
  int j = blockIdx.x * 256 + threadIdx.x;
  if (j == 0) errAcc[0] = 0.0f;
  if (j < M_V) {
    float s = 0.0f;
    #pragma unroll
    for (int q = 0; q < 16; ++q) s += cp[(size_t)q * NPAD + j];
    v[j] = B_VAL / (s * A_VAL + EPSV);
  }
}

// ---- rowpass on f16 K: grid (2, N_T) ----
__global__ __launch_bounds__(256) void rowpass_kernel(const _Float16* __restrict__ Kh,
                                                      const float* __restrict__ v,
                                                      float* __restrict__ rowPart) {
  const int i = blockIdx.y;
  const int c = blockIdx.x;  // 0 or 1
  const half8v* K8 = (const half8v*)(Kh + (size_t)i * M_V);
  const float4* v4 = (const float4*)v;
  float p = 0.0f;
  int q = c * 3125 + threadIdx.x;
  #pragma unroll
  for (int it = 0; it < 12; ++it, q += 256) {
    half8v k8 = K8[q];
    float4 va = v4[q * 2], vb = v4[q * 2 + 1];
    p += (float)k8[0] * va.x + (float)k8[1] * va.y + (float)k8[2] * va.z + (float)k8[3] * va.w
       + (float)k8[4] * vb.x + (float)k8[5] * vb.y + (float)k8[6] * vb.z + (float)k8[7] * vb.w;
  }
  if (threadIdx.x < 53) {
    int q2 = c * 3125 + 3072 + threadIdx.x;
    half8v k8 = K8[q2];
    float4 va = v4[q2 * 2], vb = v4[q2 * 2 + 1];
    p += (float)k8[0] * va.x + (float)k8[1] * va.y + (float)k8[2] * va.z + (float)k8[3] * va.w
       + (float)k8[4] * vb.x + (float)k8[5] * vb.y + (float)k8[6] * vb.z + (float)k8[7] * vb.w;
  }
  p = blockReduce256(p);
  if (threadIdx.x == 0) rowPart[c * N_T + i] = p;
}

__global__ void u_kernel(const float* __restrict__ rowPart, float* __restrict__ u) {
  int i = blockIdx.x * 256 + threadIdx.x;
  u[i] = A_VAL / (rowPart[i] + rowPart[N_T + i] + EPSV);
}

// ---- speculative final: transp (f32 out) + loss partials + s=K^T u partials ----
__global__ __launch_bounds__(256) void specfinal_kernel(const _Float16* __restrict__ Kh,
                                                        const float* __restrict__ u_,
                                                        const float* __restrict__ v_,
                                                        float* __restrict__ out,
                                                        float* __restrict__ sPart,
                                                        float* __restrict__ lossPart) {
  const int j4 = blockIdx.x * 256 + threadIdx.x;
  const int by = blockIdx.y;
  float contrib = 0.0f;
  if (j4 < J4TOT) {
    float4 vv = ((const float4*)v_)[j4];
    float4 sp = {0.f, 0.f, 0.f, 0.f};
    const size_t jb = (size_t)j4 * 4;
    #pragma unroll
    for (int r = 0; r < 16; ++r) {
      int i = by * 16 + r;
      half4v k4 = *(const half4v*)(Kh + (size_t)i * M_V + jb);
      float kx = (float)k4[0], ky = (float)k4[1], kz = (float)k4[2], kw = (float)k4[3];
      float ui = u_[i];
      float tx_ = ui * kx * vv.x, ty_ = ui * ky * vv.y;
      float tz_ = ui * kz * vv.z, tw_ = ui * kw * vv.w;
      size_t o = 1 + (size_t)i * M_V + jb;
      out[o] = tx_; out[o + 1] = ty_; out[o + 2] = tz_; out[o + 3] = tw_;
      contrib += tx_ * (-__logf(kx)) + ty_ * (-__logf(ky))
               + tz_ * (-__logf(kz)) + tw_ * (-__logf(kw));
      sp.x += kx * ui; sp.y += ky * ui; sp.z += kz * ui; sp.w += kw * ui;
    }
    ((float4*)(sPart + (size_t)by * M_V))[j4] = sp;
  }
  contrib = blockReduce256(contrib) * INV_ALPHA;
  if (threadIdx.x == 0) lossPart[by * FBLK + blockIdx.x] = contrib;
}

// ---- err = sum_j |v_j * s_j - b| ----
__global__ __launch_bounds__(256) void errfinish_kernel(const float* __restrict__ sPart,
                                                        const float* __restrict__ v_,
                                                        float* errAcc) {
  int j = blockIdx.x * 256 + threadIdx.x;
  float e = 0.0f;
  if (j < M_V) {
    float s = 0.0f;
    #pragma unroll
    for (int q = 0; q < 64; ++q) s += sPart[(size_t)q * M_V + j];
    e = fabsf(v_[j] * s - B_VAL);
  }
  e = blockReduce256(e);
  if (threadIdx.x == 0) atomicAdd(errAcc, e);
}

__global__ void setflag_kernel(const float* errAcc, int* notconv) {
  *notconv = (errAcc[0] > THR) ? 1 : 0;
}
__global__ void set1_kernel(int* p) { *p = 1; }

__global__ __launch_bounds__(256) void finishloss_kernel(const float* __restrict__ lossPart,
                                                         float* out, int np_) {
  float s = 0.0f;
  for (int i = threadIdx.x; i < np_; i += 256) s += lossPart[i];
  s = blockReduce256(s);
  if (threadIdx.x == 0) out[0] = s;
}

// ---- safety-net cooperative Sinkhorn (gated; perf-irrelevant when converged) ----
template <typename KT>
__global__ __launch_bounds__(256, 4) void sinkhorn_coop(const KT* Km,
                                                        float* __restrict__ u,
                                                        float* __restrict__ v,
                                                        float* __restrict__ s,
                                                        float* __restrict__ errAcc,
                                                        const int* __restrict__ notconv) {
  if (*notconv == 0) return;   // uniform across grid
  cg::grid_group grid = cg::this_grid();
  __shared__ float su[N_T];
  __shared__ float red[8][64];
  const int tid = threadIdx.x;
  const int bid = blockIdx.x;
  {
    int g0 = bid * 256 + tid;
    if (g0 < N_T) u[g0] = A_VAL;
    if (g0 < 2) errAcc[g0] = 0.0f;
  }
  grid.sync();
  for (int t = 1; t <= 100; ++t) {
    const bool check = (t == 2) || (t == 52);
    for (int i = tid; i < N_T; i += 256) su[i] = u[i];
    __syncthreads();
    const int g = tid >> 5, jl = tid & 31;
    float eacc = 0.0f;
    for (int c = bid; c < NCHUNK; c += COOP_BLOCKS) {
      const int j0 = c * 64;
      const int jj = j0 + jl * 2;
      float p0 = 0.f, p1 = 0.f;
      if (jj < M_V) {
        const KT* base = Km + (size_t)(g * 128) * M_V + jj;
        #pragma unroll 4
        for (int i = 0; i < 128; ++i) {
          float k0 = (float)base[(size_t)i * M_V];
          float k1 = (float)base[(size_t)i * M_V + 1];
          float uu = su[g * 128 + i];
          p0 += k0 * uu; p1 += k1 * uu;
        }
      }
      red[g][jl * 2]     = p0;
      red[g][jl * 2 + 1] = p1;
      __syncthreads();
      if (tid < 64) {
        int j = j0 + tid;
        if (j < M_V) {
          float st = 0.f;
          #pragma unroll
          for (int q = 0; q < 8; ++q) st += red[q][tid];
          if (check) {
            s[j] = st;
            eacc += fabsf(v[j] * st - B_VAL);
          } else {
            v[j] = B_VAL / (st + EPSV);
          }
        }
      }
      __syncthreads();
    }
    if (check) {
      float e = blockReduce256(eacc);
      if (tid == 0) atomicAdd(&errAcc[t == 2 ? 0 : 1], e);
    }
    grid.sync();
    if (check) {
      float e = errAcc[t == 2 ? 0 : 1];
      if (e <= THR) break;
      if (tid < 64) {
        for (int c = bid; c < NCHUNK; c += COOP_BLOCKS) {
          int j = c * 64 + tid;
          if (j < M_V) v[j] = B_VAL / (s[j] + EPSV);
        }
      }
      grid.sync();
    }
    {
      int i = bid;
      float p = 0.f;
      if (i < N_T) {
        const KT* row = Km + (size_t)i * M_V;
        for (int j = tid; j < M_V; j += 256) p += (float)row[j] * v[j];
      }
      p = blockReduce256(p);
      if (tid == 0 && i < N_T) u[i] = A_VAL / (p + EPSV);
    }
    grid.sync();
  }
}

// ---- gated redo final ----
template <typename KT>
__global__ __launch_bounds__(256) void final_kernel(const KT* Kmat,
                                                    const float* __restrict__ u,
                                                    const float* __restrict__ v,
                                                    float* out,
                                                    float* __restrict__ partials,
                                                    const int* __restrict__ gate) {
  if (*gate == 0) return;
  int j = blockIdx.x * 256 + threadIdx.x;
  float contrib = 0.0f;
  if (j < M_V) {
    float vj = v[j];
    #pragma unroll 4
    for (int r = 0; r < 16; ++r) {
      int i = blockIdx.y * 16 + r;
      size_t idx = (size_t)i * M_V + j;
      float k = (float)Kmat[idx];
      float tr = u[i] * k * vj;
      float m = -__logf(k) * INV_ALPHA;
      out[1 + idx] = tr;
      contrib += tr * m;
    }
  }
  contrib = blockReduce256(contrib);
  if (threadIdx.x == 0) partials[blockIdx.y * gridDim.x + blockIdx.x] = contrib;
}

__global__ __launch_bounds__(256) void finish_kernel(const float* __restrict__ partials,
                                                     float* out, int np_,
                                                     const int* __restrict__ gate) {
  if (*gate == 0) return;
  float s = 0.0f;
  for (int i = threadIdx.x; i < np_; i += 256) s += partials[i];
  s = blockReduce256(s);
  if (threadIdx.x == 0) out[0] = s;
}

extern "C" void kernel_launch(void* const* d_in, const int* in_sizes, int n_in,
                              void* d_out, int out_size, void* d_ws, size_t ws_size,
                              hipStream_t stream) {
  const float* x = (const float*)d_in[0];
  const float* y = (const float*)d_in[1];
  float* out = (float*)d_out;

  uintptr_t wp = (uintptr_t)d_ws;
  uintptr_t wend = (uintptr_t)d_ws + ws_size;
  auto alloc = [&](size_t bytes) -> void* {
    wp = (wp + 255) & ~(uintptr_t)255;
    void* p = (void*)wp;
    wp += bytes;
    return p;
  };
  float* u        = (float*)alloc((size_t)N_T * 4);
  float* v        = (float*)alloc((size_t)M_V * 4);
  float* s        = (float*)alloc((size_t)M_V * 4);
  float* xx       = (float*)alloc((size_t)N_T * 4);
  float* yy       = (float*)alloc((size_t)M_V * 4);
  float* partials = (float*)alloc((size_t)NPART * 4);
  float* lossPart = (float*)alloc((size_t)LPART * 4);
  float* rowPart  = (float*)alloc((size_t)2 * N_T * 4);
  float* errAcc   = (float*)alloc(64);
  int*   notconv  = (int*)alloc(64);
  float* colsumPart = (float*)alloc((size_t)16 * NPAD * 4);
  float* sPart    = (float*)alloc((size_t)64 * M_V * 4);   // 12.8 MB

  const size_t apbytes = (size_t)N_T * 512 * 2;    // 1 MB
  const size_t bpbytes = (size_t)NPAD * 256 * 2;   // 25.6 MB
  const size_t khbytes = (size_t)N_T * M_V * 2;    // 100 MB
  const size_t kfbytes = (size_t)N_T * M_V * 4;    // 200 MB (fallback)

  bool fast = ((wp + 1024) + apbytes + bpbytes + khbytes) <= wend;

  sumsq_kernel<<<N_T, 256, 0, stream>>>(x, xx, N_T);
  sumsq_kernel<<<M_V, 256, 0, stream>>>(y, yy, M_V);

  if (fast) {
    unsigned short* Ap = (unsigned short*)alloc(apbytes);
    unsigned short* Bp = (unsigned short*)alloc(bpbytes);
    _Float16*       Kh = (_Float16*)alloc(khbytes);

    pack_x_kernel<<<N_T / 2, 256, 0, stream>>>(x, Ap);
    pack_y_kernel<<<NPAD / 2, 256, 0, stream>>>(y, Bp);
    mfma_gemm_kernel<<<49 * 64, 256, 0, stream>>>(Ap, Bp, xx, yy, Kh, colsumPart);

    v1_kernel<<<CBLK, 256, 0, stream>>>(colsumPart, v, errAcc);
    rowpass_kernel<<<dim3(2, N_T), 256, 0, stream>>>(Kh, v, rowPart);
    u_kernel<<<N_T / 256, 256, 0, stream>>>(rowPart, u);

    specfinal_kernel<<<dim3(FBLK, 64), 256, 0, stream>>>(Kh, u, v, out, sPart, lossPart);
    errfinish_kernel<<<CBLK, 256, 0, stream>>>(sPart, v, errAcc);
    setflag_kernel<<<1, 1, 0, stream>>>(errAcc, notconv);
    finishloss_kernel<<<1, 256, 0, stream>>>(lossPart, out, LPART);

    // safety net (gated off when converged at first check)
    void* coopArgs[] = {(void*)&Kh, (void*)&u, (void*)&v, (void*)&s,
                        (void*)&errAcc, (void*)&notconv};
    hipLaunchCooperativeKernel(reinterpret_cast<void*>(sinkhorn_coop<_Float16>),
                               dim3(COOP_BLOCKS), dim3(256), coopArgs, 0, stream);
    final_kernel<_Float16><<<dim3(CBLK, 64), 256, 0, stream>>>(Kh, u, v, out, partials, notconv);
    finish_kernel<<<1, 256, 0, stream>>>(partials, out, NPART, notconv);
  } else {
    // fallback: exact f32 K (in ws if it fits, else in out+1), full coop loop
    bool k_in_ws = ((wp + 512) + kfbytes) <= wend;
    float* Kmat = k_in_ws ? (float*)alloc(kfbytes) : out + 1;
    gemm_k_kernel<<<dim3((M_V + BN - 1) / BN, N_T / BM), 256, 0, stream>>>(x, y, xx, yy, Kmat);
    set1_kernel<<<1, 1, 0, stream>>>(notconv);
    void* coopArgs[] = {(void*)&Kmat, (void*)&u, (void*)&v, (void*)&s,
                        (void*)&errAcc, (void*)&notconv};
    hipLaunchCooperativeKernel(reinterpret_cast<void*>(sinkhorn_coop<float>),
                               dim3(COOP_BLOCKS), dim3(256), coopArgs, 0, stream);
    final_kernel<float><<<dim3(CBLK, 64), 256, 0, stream>>>(Kmat, u, v, out, partials, notconv);
    finish_kernel<<<1, 256, 0, stream>>>(partials, out, NPART, notconv);
  }
}

// Round 6
// 273.298 us; speedup vs baseline: 4.1180x; 1.1166x over previous
//
#include <hip/hip_runtime.h>
#include <hip/hip_cooperative_groups.h>
#include <cstdint>

namespace cg = cooperative_groups;

#define N_T 1024
#define M_V 50000
#define DIMS 256
#define NPAD 50048
#define GPANELS 391         // 50048 / 128
#define CBLK 196            // ceil(50000/256)
#define NPART (CBLK * 64)
#define NCHUNK 782          // coop colpass chunks
#define COOP_BLOCKS 1024
#define J8TOT 6250          // 50000/8 columns-of-8
#define F8BLK 25            // ceil(6250/256)
#define LPART (F8BLK * 64)

constexpr float ALPHA     = 0.05f;
constexpr float INV_ALPHA = 20.0f;
constexpr float A_VAL     = 1.0f / 1024.0f;
constexpr float B_VAL     = 1.0f / 50000.0f;
constexpr float THR       = 0.005f;
constexpr float EPSV      = 1e-16f;

typedef short    bf16x8 __attribute__((ext_vector_type(8)));
typedef float    f32x4  __attribute__((ext_vector_type(4)));
typedef _Float16 half8v __attribute__((ext_vector_type(8)));

__device__ __forceinline__ float blockReduce256(float val) {
  #pragma unroll
  for (int off = 32; off; off >>= 1) val += __shfl_down(val, off, 64);
  __shared__ float redw[4];
  int lane = threadIdx.x & 63;
  int wid  = threadIdx.x >> 6;
  if (lane == 0) redw[wid] = val;
  __syncthreads();
  float r = 0.0f;
  if (threadIdx.x == 0) r = redw[0] + redw[1] + redw[2] + redw[3];
  __syncthreads();
  return r;
}

__device__ __forceinline__ unsigned short f2bf(float f) {
  union { float f; unsigned u; } c{f};
  unsigned r = c.u + 0x7FFF + ((c.u >> 16) & 1);   // RNE
  return (unsigned short)(r >> 16);
}
__device__ __forceinline__ float bf2f(unsigned short b) {
  union { unsigned u; float f; } c{(unsigned)b << 16};
  return c.f;
}

__device__ __forceinline__ void gload16(const void* g, void* l) {
  __builtin_amdgcn_global_load_lds((const __attribute__((address_space(1))) unsigned int*)g,
                                   (__attribute__((address_space(3))) unsigned int*)l, 16, 0, 0);
}

// ---- row sum of squares (fallback path only) ----
__global__ __launch_bounds__(256) void sumsq_kernel(const float* __restrict__ in,
                                                    float* __restrict__ o, int rows) {
  int r = blockIdx.x;
  if (r >= rows) return;
  float v = in[(size_t)r * DIMS + threadIdx.x];
  float s = blockReduce256(v * v);
  if (threadIdx.x == 0) o[r] = s;
}

// ---- pack x -> A' = [xh | xl] (K=512) + fused xx row-norms ----
__global__ __launch_bounds__(256) void pack_x_kernel(const float* __restrict__ x,
                                                     unsigned short* __restrict__ Ap,
                                                     float* __restrict__ xx) {
  int r = blockIdx.x * 2 + (threadIdx.x >> 7);
  int k = (threadIdx.x & 127) * 2;
  float2 vx = *(const float2*)&x[(size_t)r * DIMS + k];
  ushort2 h2, l2;
  h2.x = f2bf(vx.x); h2.y = f2bf(vx.y);
  l2.x = f2bf(vx.x - bf2f(h2.x)); l2.y = f2bf(vx.y - bf2f(h2.y));
  *(ushort2*)&Ap[(size_t)r * 512 + k]       = h2;
  *(ushort2*)&Ap[(size_t)r * 512 + 256 + k] = l2;
  // row-half reduction: 2 waves per row
  float ssq = vx.x * vx.x + vx.y * vx.y;
  #pragma unroll
  for (int off = 32; off; off >>= 1) ssq += __shfl_down(ssq, off, 64);
  __shared__ float rr[4];
  int lane = threadIdx.x & 63, wid = threadIdx.x >> 6;
  if (lane == 0) rr[wid] = ssq;
  __syncthreads();
  if ((threadIdx.x & 127) == 0) xx[r] = rr[wid] + rr[wid + 1];
}

// ---- pack y -> B' = [yh] (K=256, zero-padded) + fused yy row-norms ----
__global__ __launch_bounds__(256) void pack_y_kernel(const float* __restrict__ y,
                                                     unsigned short* __restrict__ Bp,
                                                     float* __restrict__ yy) {
  int r = blockIdx.x * 2 + (threadIdx.x >> 7);
  int k = (threadIdx.x & 127) * 2;
  ushort2 h2 = {0, 0};
  float ssq = 0.0f;
  if (r < M_V) {
    float2 vy = *(const float2*)&y[(size_t)r * DIMS + k];
    h2.x = f2bf(vy.x); h2.y = f2bf(vy.y);
    ssq = vy.x * vy.x + vy.y * vy.y;
  }
  *(ushort2*)&Bp[(size_t)r * 256 + k] = h2;
  #pragma unroll
  for (int off = 32; off; off >>= 1) ssq += __shfl_down(ssq, off, 64);
  __shared__ float rr[4];
  int lane = threadIdx.x & 63, wid = threadIdx.x >> 6;
  if (lane == 0) rr[wid] = ssq;
  __syncthreads();
  if ((threadIdx.x & 127) == 0 && r < M_V) yy[r] = rr[wid] + rr[wid + 1];
}

// ---- MFMA GEMM -> f16 K + fused column-sum partials ----
// 2-phase double-buffered pipeline (counted vmcnt(6), raw s_barrier).
// XCD-aware 1-D grid: the 8 row-tiles of a panel share blockIdx%8 -> same XCD L2.
__global__ __launch_bounds__(256) void mfma_gemm_kernel(const unsigned short* __restrict__ Ap,
                                                        const unsigned short* __restrict__ Bp,
                                                        const float* __restrict__ xx,
                                                        const float* __restrict__ yy,
                                                        _Float16* __restrict__ Kh,
                                                        float* __restrict__ colsumPart) {
  const int t  = blockIdx.x & 63;
  const int gb = blockIdx.x >> 6;
  const int panel = gb * 8 + (t & 7);
  const int rt    = t >> 3;
  if (panel >= GPANELS) return;
  const int i0 = rt * 128;
  const int j0 = panel * 128;

  __shared__ unsigned short Ah[2][128][32];
  __shared__ unsigned short Al[2][128][32];
  __shared__ unsigned short Bs[2][128][32];
  const int tid  = threadIdx.x;
  const int lane = tid & 63;
  const int wid  = tid >> 6;
  const int wr = wid >> 1, wc = wid & 1;

  f32x4 acc[4][4];
  #pragma unroll
  for (int m = 0; m < 4; ++m)
    #pragma unroll
    for (int n = 0; n < 4; ++n) acc[m][n] = (f32x4){0.f, 0.f, 0.f, 0.f};

  const int srow  = lane >> 2;
  const int sslot = lane & 3;

  // stage one 32-wide K-chunk into buffer b (6 gloads/wave -> vmcnt +6)
  auto STAGE = [&](int b, int k0) {
    #pragma unroll
    for (int q = 0; q < 2; ++q) {
      int rbase = (wid * 2 + q) * 16;
      int row = rbase + srow;
      int cg_ = sslot ^ ((row >> 1) & 3);
      gload16(Ap + (size_t)(i0 + row) * 512 + k0 + cg_ * 8,       &Ah[b][rbase][0]);
      gload16(Ap + (size_t)(i0 + row) * 512 + 256 + k0 + cg_ * 8, &Al[b][rbase][0]);
      gload16(Bp + (size_t)(j0 + row) * 256 + k0 + cg_ * 8,       &Bs[b][rbase][0]);
    }
  };

  STAGE(0, 0);
  int cur = 0;
  #pragma unroll
  for (int step = 0; step < 8; ++step) {
    if (step < 7) {
      STAGE(cur ^ 1, (step + 1) * 32);
      asm volatile("s_waitcnt vmcnt(6)" ::: "memory");   // buf[cur]'s 6 landed
    } else {
      asm volatile("s_waitcnt vmcnt(0)" ::: "memory");
    }
    __builtin_amdgcn_s_barrier();
    __builtin_amdgcn_sched_barrier(0);                   // keep ds_reads below barrier
    bf16x8 ah[4], al[4], bb[4];
    #pragma unroll
    for (int m = 0; m < 4; ++m) {
      int row = wr * 64 + m * 16 + (lane & 15);
      int sl  = (lane >> 4) ^ ((row >> 1) & 3);
      ah[m] = *(const bf16x8*)&Ah[cur][row][sl * 8];
      al[m] = *(const bf16x8*)&Al[cur][row][sl * 8];
    }
    #pragma unroll
    for (int n = 0; n < 4; ++n) {
      int col = wc * 64 + n * 16 + (lane & 15);
      int sl  = (lane >> 4) ^ ((col >> 1) & 3);
      bb[n] = *(const bf16x8*)&Bs[cur][col][sl * 8];
    }
    #pragma unroll
    for (int m = 0; m < 4; ++m)
      #pragma unroll
      for (int n = 0; n < 4; ++n) {
        acc[m][n] = __builtin_amdgcn_mfma_f32_16x16x32_bf16(ah[m], bb[n], acc[m][n], 0, 0, 0);
        acc[m][n] = __builtin_amdgcn_mfma_f32_16x16x32_bf16(al[m], bb[n], acc[m][n], 0, 0, 0);
      }
    asm volatile("s_waitcnt lgkmcnt(0)" ::: "memory");   // ds_reads of buf[cur] done
    __builtin_amdgcn_sched_barrier(0);
    __builtin_amdgcn_s_barrier();                        // safe to overwrite buf[cur]
    cur ^= 1;
  }

  // epilogue: D col=lane&15, row=(lane>>4)*4+reg; f16 store; colsum of ROUNDED values
  float csum[4] = {0.f, 0.f, 0.f, 0.f};
  #pragma unroll
  for (int m = 0; m < 4; ++m) {
    int rowb = i0 + wr * 64 + m * 16 + (lane >> 4) * 4;
    #pragma unroll
    for (int n = 0; n < 4; ++n) {
      int col = j0 + wc * 64 + n * 16 + (lane & 15);
      float yyc = (col < M_V) ? yy[col] : 0.0f;
      #pragma unroll
      for (int r = 0; r < 4; ++r) {
        float mval = xx[rowb + r] + yyc - 2.0f * acc[m][n][r];
        _Float16 kh = (_Float16)__expf(-ALPHA * mval);
        if (col < M_V) Kh[(size_t)(rowb + r) * M_V + col] = kh;
        csum[n] += (float)kh;
      }
    }
  }
  #pragma unroll
  for (int n = 0; n < 4; ++n) {
    float c = csum[n];
    c += __shfl_xor(c, 16, 64);
    c += __shfl_xor(c, 32, 64);
    if (lane < 16) {
      int col = j0 + wc * 64 + n * 16 + lane;
      colsumPart[(size_t)(rt * 2 + wr) * NPAD + col] = c;
    }
  }
}

// ---- fallback f32 GEMM (exact; only if ws too small) ----
#define BM 64
#define BN 64
#define BK 32
__global__ __launch_bounds__(256) void gemm_k_kernel(const float* __restrict__ x,
                                                     const float* __restrict__ y,
                                                     const float* __restrict__ xx,
                                                     const float* __restrict__ yy,
                                                     float* Kmat) {
  __shared__ float As[BK][BM];
  __shared__ float Bs[BK][BN + 1];
  int tid = threadIdx.x;
  int i0 = blockIdx.y * BM;
  int j0 = blockIdx.x * BN;
  int tx = tid & 15, ty = tid >> 4;
  float acc[4][4] = {};
  for (int k0 = 0; k0 < DIMS; k0 += BK) {
    #pragma unroll
    for (int l = tid; l < 512; l += 256) {
      int r = l >> 3, kq = l & 7;
      float4 a4 = *(const float4*)&x[(size_t)(i0 + r) * DIMS + k0 + kq * 4];
      As[kq * 4 + 0][r] = a4.x; As[kq * 4 + 1][r] = a4.y;
      As[kq * 4 + 2][r] = a4.z; As[kq * 4 + 3][r] = a4.w;
    }
    #pragma unroll
    for (int l = tid; l < 512; l += 256) {
      int r = l >> 3, kq = l & 7;
      int j = j0 + r;
      float4 b4 = make_float4(0.f, 0.f, 0.f, 0.f);
      if (j < M_V) b4 = *(const float4*)&y[(size_t)j * DIMS + k0 + kq * 4];
      Bs[kq * 4 + 0][r] = b4.x; Bs[kq * 4 + 1][r] = b4.y;
      Bs[kq * 4 + 2][r] = b4.z; Bs[kq * 4 + 3][r] = b4.w;
    }
    __syncthreads();
    #pragma unroll
    for (int k = 0; k < BK; ++k) {
      float a[4], b[4];
      #pragma unroll
      for (int r = 0; r < 4; ++r) a[r] = As[k][ty * 4 + r];
      #pragma unroll
      for (int c = 0; c < 4; ++c) b[c] = Bs[k][tx * 4 + c];
      #pragma unroll
      for (int r = 0; r < 4; ++r)
        #pragma unroll
        for (int c = 0; c < 4; ++c) acc[r][c] += a[r] * b[c];
    }
    __syncthreads();
  }
  #pragma unroll
  for (int r = 0; r < 4; ++r) {
    int i = i0 + ty * 4 + r;
    float xxi = xx[i];
    #pragma unroll
    for (int c = 0; c < 4; ++c) {
      int j = j0 + tx * 4 + c;
      if (j < M_V) {
        float m = xxi + yy[j] - 2.0f * acc[r][c];
        Kmat[(size_t)i * M_V + j] = __expf(-ALPHA * m);
      }
    }
  }
}

// ---- v1: v_j = b / (colsum_j * a + eps); zero errAcc ----
__global__ __launch_bounds__(256) void v1_kernel(const float* __restrict__ cp,
                                                 float* __restrict__ v,
                                                 float* __restrict__ errAcc) {
  int j = blockIdx.x * 256 + threadIdx.x;
  if (j == 0) errAcc[0] = 0.0f;
  if (j < M_V) {
    float s = 0.0f;
    #pragma unroll
    for (int q = 0; q < 16; ++q) s += cp[(size_t)q * NPAD + j];
    v[j] = B_VAL / (s * A_VAL + EPSV);
  }
}

// ---- rowpass on f16 K: grid (2, N_T) ----
__global__ __launch_bounds__(256) void rowpass_kernel(const _Float16* __restrict__ Kh,
                                                      const float* __restrict__ v,
                                                      float* __restrict__ rowPart) {
  const int i = blockIdx.y;
  const int c = blockIdx.x;  // 0 or 1
  const half8v* K8 = (const half8v*)(Kh + (size_t)i * M_V);
  const float4* v4 = (const float4*)v;
  float p = 0.0f;
  int q = c * 3125 + threadIdx.x;
  #pragma unroll
  for (int it = 0; it < 12; ++it, q += 256) {
    half8v k8 = K8[q];
    float4 va = v4[q * 2], vb = v4[q * 2 + 1];
    p += (float)k8[0] * va.x + (float)k8[1] * va.y + (float)k8[2] * va.z + (float)k8[3] * va.w
       + (float)k8[4] * vb.x + (float)k8[5] * vb.y + (float)k8[6] * vb.z + (float)k8[7] * vb.w;
  }
  if (threadIdx.x < 53) {
    int q2 = c * 3125 + 3072 + threadIdx.x;
    half8v k8 = K8[q2];
    float4 va = v4[q2 * 2], vb = v4[q2 * 2 + 1];
    p += (float)k8[0] * va.x + (float)k8[1] * va.y + (float)k8[2] * va.z + (float)k8[3] * va.w
       + (float)k8[4] * vb.x + (float)k8[5] * vb.y + (float)k8[6] * vb.z + (float)k8[7] * vb.w;
  }
  p = blockReduce256(p);
  if (threadIdx.x == 0) rowPart[c * N_T + i] = p;
}

__global__ void u_kernel(const float* __restrict__ rowPart, float* __restrict__ u) {
  int i = blockIdx.x * 256 + threadIdx.x;
  u[i] = A_VAL / (rowPart[i] + rowPart[N_T + i] + EPSV);
}

// ---- speculative final: 8 cols/thread; transp + loss partials + s partials ----
__global__ __launch_bounds__(256) void specfinal_kernel(const _Float16* __restrict__ Kh,
                                                        const float* __restrict__ u_,
                                                        const float* __restrict__ v_,
                                                        float* __restrict__ out,
                                                        float* __restrict__ sPart,
                                                        float* __restrict__ lossPart) {
  const int j8 = blockIdx.x * 256 + threadIdx.x;
  const int by = blockIdx.y;
  float contrib = 0.0f;
  if (j8 < J8TOT) {
    const size_t jb = (size_t)j8 * 8;
    float4 va = ((const float4*)v_)[j8 * 2];
    float4 vb = ((const float4*)v_)[j8 * 2 + 1];
    float sp0 = 0.f, sp1 = 0.f, sp2 = 0.f, sp3 = 0.f;
    float sp4 = 0.f, sp5 = 0.f, sp6 = 0.f, sp7 = 0.f;
    #pragma unroll
    for (int r = 0; r < 16; ++r) {
      int i = by * 16 + r;
      half8v k8 = *(const half8v*)(Kh + (size_t)i * M_V + jb);
      float ui = u_[i];
      float k0 = (float)k8[0], k1 = (float)k8[1], k2 = (float)k8[2], k3 = (float)k8[3];
      float k4 = (float)k8[4], k5 = (float)k8[5], k6 = (float)k8[6], k7 = (float)k8[7];
      float t0 = ui * k0 * va.x, t1 = ui * k1 * va.y, t2 = ui * k2 * va.z, t3 = ui * k3 * va.w;
      float t4 = ui * k4 * vb.x, t5 = ui * k5 * vb.y, t6 = ui * k6 * vb.z, t7 = ui * k7 * vb.w;
      size_t o = 1 + (size_t)i * M_V + jb;
      out[o]     = t0; out[o + 1] = t1; out[o + 2] = t2; out[o + 3] = t3;
      out[o + 4] = t4; out[o + 5] = t5; out[o + 6] = t6; out[o + 7] = t7;
      contrib += t0 * (-__logf(k0)) + t1 * (-__logf(k1)) + t2 * (-__logf(k2)) + t3 * (-__logf(k3))
               + t4 * (-__logf(k4)) + t5 * (-__logf(k5)) + t6 * (-__logf(k6)) + t7 * (-__logf(k7));
      sp0 += k0 * ui; sp1 += k1 * ui; sp2 += k2 * ui; sp3 += k3 * ui;
      sp4 += k4 * ui; sp5 += k5 * ui; sp6 += k6 * ui; sp7 += k7 * ui;
    }
    float* sb = sPart + (size_t)by * M_V + jb;
    *(float4*)sb       = make_float4(sp0, sp1, sp2, sp3);
    *(float4*)(sb + 4) = make_float4(sp4, sp5, sp6, sp7);
  }
  contrib = blockReduce256(contrib) * INV_ALPHA;
  if (threadIdx.x == 0) lossPart[by * F8BLK + blockIdx.x] = contrib;
}

// ---- err = sum_j |v_j * s_j - b| ----
__global__ __launch_bounds__(256) void errfinish_kernel(const float* __restrict__ sPart,
                                                        const float* __restrict__ v_,
                                                        float* errAcc) {
  int j = blockIdx.x * 256 + threadIdx.x;
  float e = 0.0f;
  if (j < M_V) {
    float s = 0.0f;
    #pragma unroll
    for (int q = 0; q < 64; ++q) s += sPart[(size_t)q * M_V + j];
    e = fabsf(v_[j] * s - B_VAL);
  }
  e = blockReduce256(e);
  if (threadIdx.x == 0) atomicAdd(errAcc, e);
}

__global__ void setflag_kernel(const float* errAcc, int* notconv) {
  *notconv = (errAcc[0] > THR) ? 1 : 0;
}
__global__ void set1_kernel(int* p) { *p = 1; }

__global__ __launch_bounds__(256) void finishloss_kernel(const float* __restrict__ lossPart,
                                                         float* out, int np_) {
  float s = 0.0f;
  for (int i = threadIdx.x; i < np_; i += 256) s += lossPart[i];
  s = blockReduce256(s);
  if (threadIdx.x == 0) out[0] = s;
}

// ---- safety-net cooperative Sinkhorn (gated; perf-irrelevant when converged) ----
template <typename KT>
__global__ __launch_bounds__(256, 4) void sinkhorn_coop(const KT* Km,
                                                        float* __restrict__ u,
                                                        float* __restrict__ v,
                                                        float* __restrict__ s,
                                                        float* __restrict__ errAcc,
                                                        const int* __restrict__ notconv) {
  if (*notconv == 0) return;   // uniform across grid
  cg::grid_group grid = cg::this_grid();
  __shared__ float su[N_T];
  __shared__ float red[8][64];
  const int tid = threadIdx.x;
  const int bid = blockIdx.x;
  {
    int g0 = bid * 256 + tid;
    if (g0 < N_T) u[g0] = A_VAL;
    if (g0 < 2) errAcc[g0] = 0.0f;
  }
  grid.sync();
  for (int t = 1; t <= 100; ++t) {
    const bool check = (t == 2) || (t == 52);
    for (int i = tid; i < N_T; i += 256) su[i] = u[i];
    __syncthreads();
    const int g = tid >> 5, jl = tid & 31;
    float eacc = 0.0f;
    for (int c = bid; c < NCHUNK; c += COOP_BLOCKS) {
      const int j0 = c * 64;
      const int jj = j0 + jl * 2;
      float p0 = 0.f, p1 = 0.f;
      if (jj < M_V) {
        const KT* base = Km + (size_t)(g * 128) * M_V + jj;
        #pragma unroll 4
        for (int i = 0; i < 128; ++i) {
          float k0 = (float)base[(size_t)i * M_V];
          float k1 = (float)base[(size_t)i * M_V + 1];
          float uu = su[g * 128 + i];
          p0 += k0 * uu; p1 += k1 * uu;
        }
      }
      red[g][jl * 2]     = p0;
      red[g][jl * 2 + 1] = p1;
      __syncthreads();
      if (tid < 64) {
        int j = j0 + tid;
        if (j < M_V) {
          float st = 0.f;
          #pragma unroll
          for (int q = 0; q < 8; ++q) st += red[q][tid];
          if (check) {
            s[j] = st;
            eacc += fabsf(v[j] * st - B_VAL);
          } else {
            v[j] = B_VAL / (st + EPSV);
          }
        }
      }
      __syncthreads();
    }
    if (check) {
      float e = blockReduce256(eacc);
      if (tid == 0) atomicAdd(&errAcc[t == 2 ? 0 : 1], e);
    }
    grid.sync();
    if (check) {
      float e = errAcc[t == 2 ? 0 : 1];
      if (e <= THR) break;
      if (tid < 64) {
        for (int c = bid; c < NCHUNK; c += COOP_BLOCKS) {
          int j = c * 64 + tid;
          if (j < M_V) v[j] = B_VAL / (s[j] + EPSV);
        }
      }
      grid.sync();
    }
    {
      int i = bid;
      float p = 0.f;
      if (i < N_T) {
        const KT* row = Km + (size_t)i * M_V;
        for (int j = tid; j < M_V; j += 256) p += (float)row[j] * v[j];
      }
      p = blockReduce256(p);
      if (tid == 0 && i < N_T) u[i] = A_VAL / (p + EPSV);
    }
    grid.sync();
  }
}

// ---- gated redo final ----
template <typename KT>
__global__ __launch_bounds__(256) void final_kernel(const KT* Kmat,
                                                    const float* __restrict__ u,
                                                    const float* __restrict__ v,
                                                    float* out,
                                                    float* __restrict__ partials,
                                                    const int* __restrict__ gate) {
  if (*gate == 0) return;
  int j = blockIdx.x * 256 + threadIdx.x;
  float contrib = 0.0f;
  if (j < M_V) {
    float vj = v[j];
    #pragma unroll 4
    for (int r = 0; r < 16; ++r) {
      int i = blockIdx.y * 16 + r;
      size_t idx = (size_t)i * M_V + j;
      float k = (float)Kmat[idx];
      float tr = u[i] * k * vj;
      float m = -__logf(k) * INV_ALPHA;
      out[1 + idx] = tr;
      contrib += tr * m;
    }
  }
  contrib = blockReduce256(contrib);
  if (threadIdx.x == 0) partials[blockIdx.y * gridDim.x + blockIdx.x] = contrib;
}

__global__ __launch_bounds__(256) void finish_kernel(const float* __restrict__ partials,
                                                     float* out, int np_,
                                                     const int* __restrict__ gate) {
  if (*gate == 0) return;
  float s = 0.0f;
  for (int i = threadIdx.x; i < np_; i += 256) s += partials[i];
  s = blockReduce256(s);
  if (threadIdx.x == 0) out[0] = s;
}

extern "C" void kernel_launch(void* const* d_in, const int* in_sizes, int n_in,
                              void* d_out, int out_size, void* d_ws, size_t ws_size,
                              hipStream_t stream) {
  const float* x = (const float*)d_in[0];
  const float* y = (const float*)d_in[1];
  float* out = (float*)d_out;

  uintptr_t wp = (uintptr_t)d_ws;
  uintptr_t wend = (uintptr_t)d_ws + ws_size;
  auto alloc = [&](size_t bytes) -> void* {
    wp = (wp + 255) & ~(uintptr_t)255;
    void* p = (void*)wp;
    wp += bytes;
    return p;
  };
  float* u        = (float*)alloc((size_t)N_T * 4);
  float* v        = (float*)alloc((size_t)M_V * 4);
  float* s        = (float*)alloc((size_t)M_V * 4);
  float* xx       = (float*)alloc((size_t)N_T * 4);
  float* yy       = (float*)alloc((size_t)M_V * 4);
  float* partials = (float*)alloc((size_t)NPART * 4);
  float* lossPart = (float*)alloc((size_t)LPART * 4);
  float* rowPart  = (float*)alloc((size_t)2 * N_T * 4);
  float* errAcc   = (float*)alloc(64);
  int*   notconv  = (int*)alloc(64);
  float* colsumPart = (float*)alloc((size_t)16 * NPAD * 4);
  float* sPart    = (float*)alloc((size_t)64 * M_V * 4);   // 12.8 MB

  const size_t apbytes = (size_t)N_T * 512 * 2;    // 1 MB
  const size_t bpbytes = (size_t)NPAD * 256 * 2;   // 25.6 MB
  const size_t khbytes = (size_t)N_T * M_V * 2;    // 100 MB
  const size_t kfbytes = (size_t)N_T * M_V * 4;    // 200 MB (fallback)

  bool fast = ((wp + 1024) + apbytes + bpbytes + khbytes) <= wend;

  if (fast) {
    unsigned short* Ap = (unsigned short*)alloc(apbytes);
    unsigned short* Bp = (unsigned short*)alloc(bpbytes);
    _Float16*       Kh = (_Float16*)alloc(khbytes);

    pack_x_kernel<<<N_T / 2, 256, 0, stream>>>(x, Ap, xx);
    pack_y_kernel<<<NPAD / 2, 256, 0, stream>>>(y, Bp, yy);
    mfma_gemm_kernel<<<49 * 64, 256, 0, stream>>>(Ap, Bp, xx, yy, Kh, colsumPart);

    v1_kernel<<<CBLK, 256, 0, stream>>>(colsumPart, v, errAcc);
    rowpass_kernel<<<dim3(2, N_T), 256, 0, stream>>>(Kh, v, rowPart);
    u_kernel<<<N_T / 256, 256, 0, stream>>>(rowPart, u);

    specfinal_kernel<<<dim3(F8BLK, 64), 256, 0, stream>>>(Kh, u, v, out, sPart, lossPart);
    errfinish_kernel<<<CBLK, 256, 0, stream>>>(sPart, v, errAcc);
    setflag_kernel<<<1, 1, 0, stream>>>(errAcc, notconv);
    finishloss_kernel<<<1, 256, 0, stream>>>(lossPart, out, LPART);

    // safety net (gated off when converged at first check)
    void* coopArgs[] = {(void*)&Kh, (void*)&u, (void*)&v, (void*)&s,
                        (void*)&errAcc, (void*)&notconv};
    hipLaunchCooperativeKernel(reinterpret_cast<void*>(sinkhorn_coop<_Float16>),
                               dim3(COOP_BLOCKS), dim3(256), coopArgs, 0, stream);
    final_kernel<_Float16><<<dim3(CBLK, 64), 256, 0, stream>>>(Kh, u, v, out, partials, notconv);
    finish_kernel<<<1, 256, 0, stream>>>(partials, out, NPART, notconv);
  } else {
    // fallback: exact f32 K (in ws if it fits, else in out+1), full coop loop
    sumsq_kernel<<<N_T, 256, 0, stream>>>(x, xx, N_T);
    sumsq_kernel<<<M_V, 256, 0, stream>>>(y, yy, M_V);
    bool k_in_ws = ((wp + 512) + kfbytes) <= wend;
    float* Kmat = k_in_ws ? (float*)alloc(kfbytes) : out + 1;
    gemm_k_kernel<<<dim3((M_V + BN - 1) / BN, N_T / BM), 256, 0, stream>>>(x, y, xx, yy, Kmat);
    set1_kernel<<<1, 1, 0, stream>>>(notconv);
    void* coopArgs[] = {(void*)&Kmat, (void*)&u, (void*)&v, (void*)&s,
                        (void*)&errAcc, (void*)&notconv};
    hipLaunchCooperativeKernel(reinterpret_cast<void*>(sinkhorn_coop<float>),
                               dim3(COOP_BLOCKS), dim3(256), coopArgs, 0, stream);
    final_kernel<float><<<dim3(CBLK, 64), 256, 0, stream>>>(Kmat, u, v, out, partials, notconv);
    finish_kernel<<<1, 256, 0, stream>>>(partials, out, NPART, notconv);
  }
}